// Round 3
// baseline (785.352 us; speedup 1.0000x reference)
//
#include <hip/hip_runtime.h>
#include <cmath>

#define N_Q 4096
#define HEADS 8
#define HEAD_DIM 24
#define HIDDEN 192

__device__ __forceinline__ float4 ld4(const float* p) { return *(const float4*)p; }

__device__ __forceinline__ void fma4(float4& u, float w, const float* p) {
    float4 t = ld4(p);
    u.x = fmaf(w, t.x, u.x);
    u.y = fmaf(w, t.y, u.y);
    u.z = fmaf(w, t.z, u.z);
    u.w = fmaf(w, t.w, u.w);
}

// y[o, n] = sum_c W[o,c] * x[c,n]  (+ optional bias + tanh*0.35 for MODE 1)
template<int K, int OG, int MODE>
__global__ __launch_bounds__(256)
void conv1x1_kernel(const float* __restrict__ W, const float* __restrict__ bias,
                    const float* __restrict__ x, float* __restrict__ y)
{
    __shared__ float Wl[OG][K];
    int tid = threadIdx.x;
    int og = blockIdx.y;
    for (int k = tid; k < OG * K; k += 256) Wl[k / K][k % K] = W[og * OG * K + k];
    __syncthreads();
    int n = blockIdx.x * 256 + tid;
    float acc[OG];
#pragma unroll
    for (int i = 0; i < OG; i++) acc[i] = 0.f;
    for (int c = 0; c < K; c++) {
        float xv = x[c * N_Q + n];
#pragma unroll
        for (int i = 0; i < OG; i++) acc[i] = fmaf(Wl[i][c], xv, acc[i]);
    }
#pragma unroll
    for (int i = 0; i < OG; i++) {
        int o = og * OG + i;
        float r = acc[i];
        if constexpr (MODE == 1) r = tanhf(r + bias[o]) * 0.35f;
        y[o * N_Q + n] = r;
    }
}

// attention weights: logits = Wwt·q + bwt, softmax over the 16 (s,p) rows per head
__global__ __launch_bounds__(512)
void aw_kernel(const float* __restrict__ Wwt, const float* __restrict__ bwt,
               const float* __restrict__ q, float* __restrict__ aw)
{
    int tid = threadIdx.x;
    int h = tid >> 6;          // one wave per head
    int lane = tid & 63;
    int n = blockIdx.x * 64 + lane;
    float acc[16];
#pragma unroll
    for (int i = 0; i < 16; i++) acc[i] = bwt[h * 16 + i];
    for (int c = 0; c < 192; c++) {
        float qv = q[c * N_Q + n];
#pragma unroll
        for (int i = 0; i < 16; i++) acc[i] = fmaf(Wwt[(h * 16 + i) * 192 + c], qv, acc[i]);
    }
    float m = acc[0];
#pragma unroll
    for (int i = 1; i < 16; i++) m = fmaxf(m, acc[i]);
    float s = 0.f;
#pragma unroll
    for (int i = 0; i < 16; i++) { acc[i] = __expf(acc[i] - m); s += acc[i]; }
    float inv = 1.0f / s;
#pragma unroll
    for (int i = 0; i < 16; i++) aw[(h * 16 + i) * N_Q + n] = acc[i] * inv;
}

// [C, Nv] -> [Nv, C] via LDS tile (coalesced both sides)
template<int C, int P>
__global__ __launch_bounds__(256)
void transpose_kernel(const float* __restrict__ src, float* __restrict__ dst, int Nv)
{
    __shared__ float lds[P][C + 1];
    int tid = threadIdx.x;
    int pos0 = blockIdx.x * P;
    for (int k = tid; k < P * C; k += 256) {
        int c = k / P, p = k % P;
        lds[p][c] = src[c * Nv + pos0 + p];
    }
    __syncthreads();
    for (int k = tid; k < P * C; k += 256) {
        int p = k / C, c = k % C;
        dst[(pos0 + p) * C + c] = lds[p][c];
    }
}

// valT[pos, o] = sum_c Wv[o,c] * v[c, pos]   (small scales only)
__global__ __launch_bounds__(256)
void valT_kernel(const float* __restrict__ Wv, const float* __restrict__ v,
                 float* __restrict__ valT, int C, int Nv)
{
    int tid = threadIdx.x;
    int p = blockIdx.x * 64 + (tid & 63);
    int o = blockIdx.y * 4 + (tid >> 6);
    const float* wrow = Wv + o * C;
    float acc = 0.f;
    for (int c = 0; c < C; c++) acc = fmaf(wrow[c], v[c * Nv + p], acc);
    valT[p * HIDDEN + o] = acc;
}

// main deformable sampling; blockIdx = (n-tile, head, scale)
// s=0/1: fused conv (interpolate raw C channels, then head's 24xC block)
// s=2/3: sample precomputed valT rows (24 contiguous channels per head)
__global__ __launch_bounds__(256)
void sample_kernel(const float* __restrict__ offb, const float* __restrict__ awb,
                   const float* __restrict__ v0T, const float* __restrict__ v1T,
                   const float* __restrict__ val2T, const float* __restrict__ val3T,
                   const float* __restrict__ Wv0, const float* __restrict__ Wv1,
                   float* __restrict__ accb)
{
    int tid = threadIdx.x;
    int n = blockIdx.x * 256 + tid;
    int h = blockIdx.y;
    int s = blockIdx.z;

    int wx = n & 15, hy = (n >> 4) & 15, dz = n >> 8;
    const float step = 2.0f / 15.0f;
    float bx = -1.f + wx * step;
    float by = -1.f + hy * step;
    float bz = -1.f + dz * step;

    float acc[HEAD_DIM];
#pragma unroll
    for (int j = 0; j < HEAD_DIM; j++) acc[j] = 0.f;

    int S = 64; const float* srcT = v0T; const float* Wv = Wv0; int C = 32;
    if (s == 1)      { S = 32; srcT = v1T;  Wv = Wv1; C = 64; }
    else if (s == 2) { S = 16; srcT = val2T; C = 0; }
    else if (s == 3) { S = 8;  srcT = val3T; C = 0; }
    float fS = (float)S;

    for (int p = 0; p < 4; p++) {
        int orow = ((h * 4 + s) * 4 + p) * 3;
        float ox = offb[(orow + 0) * N_Q + n];
        float oy = offb[(orow + 1) * N_Q + n];
        float oz = offb[(orow + 2) * N_Q + n];
        float awv = awb[(h * 16 + s * 4 + p) * N_Q + n];

        float ix = fminf(fmaxf(((bx + ox + 1.f) * fS - 1.f) * 0.5f, 0.f), fS - 1.f);
        float iy = fminf(fmaxf(((by + oy + 1.f) * fS - 1.f) * 0.5f, 0.f), fS - 1.f);
        float iz = fminf(fmaxf(((bz + oz + 1.f) * fS - 1.f) * 0.5f, 0.f), fS - 1.f);

        float x0f = floorf(ix), y0f = floorf(iy), z0f = floorf(iz);
        float fx = ix - x0f, fy = iy - y0f, fz = iz - z0f;
        int x0 = (int)x0f, y0 = (int)y0f, z0 = (int)z0f;
        int x1 = min(x0 + 1, S - 1), y1 = min(y0 + 1, S - 1), z1 = min(z0 + 1, S - 1);

        int r000 = (z0 * S + y0) * S + x0, r001 = (z0 * S + y0) * S + x1;
        int r010 = (z0 * S + y1) * S + x0, r011 = (z0 * S + y1) * S + x1;
        int r100 = (z1 * S + y0) * S + x0, r101 = (z1 * S + y0) * S + x1;
        int r110 = (z1 * S + y1) * S + x0, r111 = (z1 * S + y1) * S + x1;

        float gx1 = fx, gx0 = 1.f - fx;
        float gy1 = fy, gy0 = 1.f - fy;
        float gz1 = fz, gz0 = 1.f - fz;
        // fold attention weight into corner weights (linearity)
        float w000 = gz0 * gy0 * gx0 * awv, w001 = gz0 * gy0 * gx1 * awv;
        float w010 = gz0 * gy1 * gx0 * awv, w011 = gz0 * gy1 * gx1 * awv;
        float w100 = gz1 * gy0 * gx0 * awv, w101 = gz1 * gy0 * gx1 * awv;
        float w110 = gz1 * gy1 * gx0 * awv, w111 = gz1 * gy1 * gx1 * awv;

        if (s < 2) {
            const float* Wvh = Wv + h * HEAD_DIM * C;
            for (int c4 = 0; c4 < C; c4 += 4) {
                float4 u = make_float4(0.f, 0.f, 0.f, 0.f);
                fma4(u, w000, srcT + r000 * C + c4);
                fma4(u, w001, srcT + r001 * C + c4);
                fma4(u, w010, srcT + r010 * C + c4);
                fma4(u, w011, srcT + r011 * C + c4);
                fma4(u, w100, srcT + r100 * C + c4);
                fma4(u, w101, srcT + r101 * C + c4);
                fma4(u, w110, srcT + r110 * C + c4);
                fma4(u, w111, srcT + r111 * C + c4);
#pragma unroll
                for (int j = 0; j < HEAD_DIM; j++) {
                    float4 wv4 = ld4(Wvh + j * C + c4);
                    acc[j] = fmaf(wv4.x, u.x, fmaf(wv4.y, u.y, fmaf(wv4.z, u.z, fmaf(wv4.w, u.w, acc[j]))));
                }
            }
        } else {
            const float* base = srcT + h * HEAD_DIM;
#pragma unroll
            for (int j4 = 0; j4 < HEAD_DIM; j4 += 4) {
                float4 u = make_float4(0.f, 0.f, 0.f, 0.f);
                fma4(u, w000, base + r000 * HIDDEN + j4);
                fma4(u, w001, base + r001 * HIDDEN + j4);
                fma4(u, w010, base + r010 * HIDDEN + j4);
                fma4(u, w011, base + r011 * HIDDEN + j4);
                fma4(u, w100, base + r100 * HIDDEN + j4);
                fma4(u, w101, base + r101 * HIDDEN + j4);
                fma4(u, w110, base + r110 * HIDDEN + j4);
                fma4(u, w111, base + r111 * HIDDEN + j4);
                acc[j4 + 0] += u.x; acc[j4 + 1] += u.y; acc[j4 + 2] += u.z; acc[j4 + 3] += u.w;
            }
        }
    }
    float* ab = accb + (size_t)s * HIDDEN * N_Q;
#pragma unroll
    for (int j = 0; j < HEAD_DIM; j++) ab[(h * HEAD_DIM + j) * N_Q + n] = acc[j];
}

// out[o,n] = sum_c Wout[o,c] * (acc0+acc1+acc2+acc3)[c,n]
__global__ __launch_bounds__(256)
void outconv_kernel(const float* __restrict__ Wout, const float* __restrict__ accb,
                    float* __restrict__ out)
{
    __shared__ float Wl[8][HIDDEN];
    int tid = threadIdx.x;
    int og = blockIdx.y;
    for (int k = tid; k < 8 * HIDDEN; k += 256) Wl[k / HIDDEN][k % HIDDEN] = Wout[og * 8 * HIDDEN + k];
    __syncthreads();
    int n = blockIdx.x * 256 + tid;
    float acc[8];
#pragma unroll
    for (int i = 0; i < 8; i++) acc[i] = 0.f;
    const int SB = HIDDEN * N_Q;
    for (int c = 0; c < HIDDEN; c++) {
        float xv = accb[c * N_Q + n] + accb[SB + c * N_Q + n]
                 + accb[2 * SB + c * N_Q + n] + accb[3 * SB + c * N_Q + n];
#pragma unroll
        for (int i = 0; i < 8; i++) acc[i] = fmaf(Wl[i][c], xv, acc[i]);
    }
#pragma unroll
    for (int i = 0; i < 8; i++) out[(og * 8 + i) * N_Q + n] = acc[i];
}

// InstanceNorm3d per channel (in-place on d_out)
__global__ __launch_bounds__(256)
void inorm_kernel(float* __restrict__ out, const float* __restrict__ gamma,
                  const float* __restrict__ beta)
{
    int o = blockIdx.x;
    int tid = threadIdx.x;
    float s = 0.f, s2 = 0.f;
    for (int n = tid; n < N_Q; n += 256) {
        float v = out[o * N_Q + n];
        s += v; s2 += v * v;
    }
    __shared__ float rs[256], rs2[256];
    rs[tid] = s; rs2[tid] = s2;
    __syncthreads();
    for (int k = 128; k > 0; k >>= 1) {
        if (tid < k) { rs[tid] += rs[tid + k]; rs2[tid] += rs2[tid + k]; }
        __syncthreads();
    }
    float mu = rs[0] * (1.0f / N_Q);
    float var = rs2[0] * (1.0f / N_Q) - mu * mu;
    float rstd = rsqrtf(var + 1e-5f);
    float g = gamma[o] * rstd;
    float b = beta[o] - mu * g;
    for (int n = tid; n < N_Q; n += 256) {
        out[o * N_Q + n] = fmaf(out[o * N_Q + n], g, b);
    }
}

extern "C" void kernel_launch(void* const* d_in, const int* in_sizes, int n_in,
                              void* d_out, int out_size, void* d_ws, size_t ws_size,
                              hipStream_t stream)
{
    const float* qf    = (const float*)d_in[0];
    const float* v0    = (const float*)d_in[1];
    const float* v1    = (const float*)d_in[2];
    const float* v2    = (const float*)d_in[3];
    const float* v3    = (const float*)d_in[4];
    const float* Wq    = (const float*)d_in[5];
    const float* Wv0   = (const float*)d_in[6];
    const float* Wv1   = (const float*)d_in[7];
    const float* Wv2   = (const float*)d_in[8];
    const float* Wv3   = (const float*)d_in[9];
    const float* Woff  = (const float*)d_in[10];
    const float* boff  = (const float*)d_in[11];
    const float* Wwt   = (const float*)d_in[12];
    const float* bwt   = (const float*)d_in[13];
    const float* Wout  = (const float*)d_in[14];
    const float* gamma = (const float*)d_in[15];
    const float* beta  = (const float*)d_in[16];
    float* out = (float*)d_out;

    float* ws    = (float*)d_ws;
    float* q     = ws;                       // 192*4096    = 786432
    float* offb  = q     + 786432;           // 384*4096    = 1572864
    float* awb   = offb  + 1572864;          // 128*4096    = 524288
    float* v0T   = awb   + 524288;           // 262144*32   = 8388608
    float* v1T   = v0T   + 8388608;          // 32768*64    = 2097152
    float* val2T = v1T   + 2097152;          // 4096*192    = 786432
    float* val3T = val2T + 786432;           // 512*192     = 98304
    float* accb  = val3T + 98304;            // 4*192*4096  = 3145728
    // total ~17.4M floats (~70 MB)

    // q = Wq @ qf
    conv1x1_kernel<128, 8, 0><<<dim3(16, 24), 256, 0, stream>>>(Wq, nullptr, qf, q);
    // offsets = tanh(Woff @ q + boff) * 0.35
    conv1x1_kernel<192, 8, 1><<<dim3(16, 48), 256, 0, stream>>>(Woff, boff, q, offb);
    // attention weights (softmax over 16 per head)
    aw_kernel<<<64, 512, 0, stream>>>(Wwt, bwt, q, awb);
    // spatial-major transposes of big value grids
    transpose_kernel<32, 256><<<1024, 256, 0, stream>>>(v0, v0T, 262144);
    transpose_kernel<64, 128><<<256, 256, 0, stream>>>(v1, v1T, 32768);
    // precomputed value conv for small scales (transposed layout)
    valT_kernel<<<dim3(64, 48), 256, 0, stream>>>(Wv2, v2, val2T, 128, 4096);
    valT_kernel<<<dim3(8, 48), 256, 0, stream>>>(Wv3, v3, val3T, 256, 512);
    // deformable sampling (fused conv for s=0/1)
    sample_kernel<<<dim3(16, 8, 4), 256, 0, stream>>>(offb, awb, v0T, v1T, val2T, val3T,
                                                      Wv0, Wv1, accb);
    // final 1x1 conv (sums the 4 per-scale accumulators)
    outconv_kernel<<<dim3(16, 16), 256, 0, stream>>>(Wout, accb, out);
    // instance norm in-place
    inorm_kernel<<<128, 256, 0, stream>>>(out, gamma, beta);
}

// Round 4
// 737.619 us; speedup vs baseline: 1.0647x; 1.0647x over previous
//
#include <hip/hip_runtime.h>
#include <cmath>

#define N_Q 4096
#define HEADS 8
#define HEAD_DIM 24
#define HIDDEN 192

__device__ __forceinline__ float4 ld4(const float* p) { return *(const float4*)p; }

__device__ __forceinline__ void fma4(float4& u, float w, const float* p) {
    float4 t = ld4(p);
    u.x = fmaf(w, t.x, u.x);
    u.y = fmaf(w, t.y, u.y);
    u.z = fmaf(w, t.z, u.z);
    u.w = fmaf(w, t.w, u.w);
}

// y[o, n] = sum_c W[o,c] * x[c,n]  (+ optional bias + tanh*0.35 for MODE 1)
template<int K, int OG, int MODE>
__global__ __launch_bounds__(256)
void conv1x1_kernel(const float* __restrict__ W, const float* __restrict__ bias,
                    const float* __restrict__ x, float* __restrict__ y)
{
    __shared__ float Wl[OG][K];
    int tid = threadIdx.x;
    int og = blockIdx.y;
    for (int k = tid; k < OG * K; k += 256) Wl[k / K][k % K] = W[og * OG * K + k];
    __syncthreads();
    int n = blockIdx.x * 256 + tid;
    float acc[OG];
#pragma unroll
    for (int i = 0; i < OG; i++) acc[i] = 0.f;
    for (int c = 0; c < K; c++) {
        float xv = x[c * N_Q + n];
#pragma unroll
        for (int i = 0; i < OG; i++) acc[i] = fmaf(Wl[i][c], xv, acc[i]);
    }
#pragma unroll
    for (int i = 0; i < OG; i++) {
        int o = og * OG + i;
        float r = acc[i];
        if constexpr (MODE == 1) r = tanhf(r + bias[o]) * 0.35f;
        y[o * N_Q + n] = r;
    }
}

// attention weights: logits = Wwt·q + bwt, softmax over the 16 (s,p) rows per head
__global__ __launch_bounds__(512)
void aw_kernel(const float* __restrict__ Wwt, const float* __restrict__ bwt,
               const float* __restrict__ q, float* __restrict__ aw)
{
    int tid = threadIdx.x;
    int h = tid >> 6;          // one wave per head
    int lane = tid & 63;
    int n = blockIdx.x * 64 + lane;
    float acc[16];
#pragma unroll
    for (int i = 0; i < 16; i++) acc[i] = bwt[h * 16 + i];
    for (int c = 0; c < 192; c++) {
        float qv = q[c * N_Q + n];
#pragma unroll
        for (int i = 0; i < 16; i++) acc[i] = fmaf(Wwt[(h * 16 + i) * 192 + c], qv, acc[i]);
    }
    float m = acc[0];
#pragma unroll
    for (int i = 1; i < 16; i++) m = fmaxf(m, acc[i]);
    float s = 0.f;
#pragma unroll
    for (int i = 0; i < 16; i++) { acc[i] = __expf(acc[i] - m); s += acc[i]; }
    float inv = 1.0f / s;
#pragma unroll
    for (int i = 0; i < 16; i++) aw[(h * 16 + i) * N_Q + n] = acc[i] * inv;
}

// [C, Nv] -> [Nv, C] via LDS tile (coalesced both sides)
template<int C, int P>
__global__ __launch_bounds__(256)
void transpose_kernel(const float* __restrict__ src, float* __restrict__ dst, int Nv)
{
    __shared__ float lds[P][C + 1];
    int tid = threadIdx.x;
    int pos0 = blockIdx.x * P;
    for (int k = tid; k < P * C; k += 256) {
        int c = k / P, p = k % P;
        lds[p][c] = src[c * Nv + pos0 + p];
    }
    __syncthreads();
    for (int k = tid; k < P * C; k += 256) {
        int p = k / C, c = k % C;
        dst[(pos0 + p) * C + c] = lds[p][c];
    }
}

// valT[pos, o] = sum_c Wv[o,c] * v[c, pos]   (small scales only)
__global__ __launch_bounds__(256)
void valT_kernel(const float* __restrict__ Wv, const float* __restrict__ v,
                 float* __restrict__ valT, int C, int Nv)
{
    int tid = threadIdx.x;
    int p = blockIdx.x * 64 + (tid & 63);
    int o = blockIdx.y * 4 + (tid >> 6);
    const float* wrow = Wv + o * C;
    float acc = 0.f;
    for (int c = 0; c < C; c++) acc = fmaf(wrow[c], v[c * Nv + p], acc);
    valT[p * HIDDEN + o] = acc;
}

// main deformable sampling; blockIdx = (n-tile, head, s*4+p)  — one point per block
// s=0/1: fused conv (interpolate raw C channels, then head's 24xC block)
// s=2/3: sample precomputed valT rows (24 contiguous channels per head)
__global__ __launch_bounds__(256)
void sample_kernel(const float* __restrict__ offb, const float* __restrict__ awb,
                   const float* __restrict__ v0T, const float* __restrict__ v1T,
                   const float* __restrict__ val2T, const float* __restrict__ val3T,
                   const float* __restrict__ Wv0, const float* __restrict__ Wv1,
                   float* __restrict__ accb)
{
    int tid = threadIdx.x;
    int n = blockIdx.x * 256 + tid;
    int h = blockIdx.y;
    int sp = blockIdx.z;
    int s = sp >> 2, p = sp & 3;

    int wx = n & 15, hy = (n >> 4) & 15, dz = n >> 8;
    const float step = 2.0f / 15.0f;
    float bx = -1.f + wx * step;
    float by = -1.f + hy * step;
    float bz = -1.f + dz * step;

    float acc[HEAD_DIM];
#pragma unroll
    for (int j = 0; j < HEAD_DIM; j++) acc[j] = 0.f;

    int S = 64; const float* srcT = v0T; const float* Wv = Wv0; int C = 32;
    if (s == 1)      { S = 32; srcT = v1T;  Wv = Wv1; C = 64; }
    else if (s == 2) { S = 16; srcT = val2T; C = 0; }
    else if (s == 3) { S = 8;  srcT = val3T; C = 0; }
    float fS = (float)S;

    int orow = ((h * 4 + s) * 4 + p) * 3;
    float ox = offb[(orow + 0) * N_Q + n];
    float oy = offb[(orow + 1) * N_Q + n];
    float oz = offb[(orow + 2) * N_Q + n];
    float awv = awb[(h * 16 + s * 4 + p) * N_Q + n];

    float ix = fminf(fmaxf(((bx + ox + 1.f) * fS - 1.f) * 0.5f, 0.f), fS - 1.f);
    float iy = fminf(fmaxf(((by + oy + 1.f) * fS - 1.f) * 0.5f, 0.f), fS - 1.f);
    float iz = fminf(fmaxf(((bz + oz + 1.f) * fS - 1.f) * 0.5f, 0.f), fS - 1.f);

    float x0f = floorf(ix), y0f = floorf(iy), z0f = floorf(iz);
    float fx = ix - x0f, fy = iy - y0f, fz = iz - z0f;
    int x0 = (int)x0f, y0 = (int)y0f, z0 = (int)z0f;
    int x1 = min(x0 + 1, S - 1), y1 = min(y0 + 1, S - 1), z1 = min(z0 + 1, S - 1);

    int r000 = (z0 * S + y0) * S + x0, r001 = (z0 * S + y0) * S + x1;
    int r010 = (z0 * S + y1) * S + x0, r011 = (z0 * S + y1) * S + x1;
    int r100 = (z1 * S + y0) * S + x0, r101 = (z1 * S + y0) * S + x1;
    int r110 = (z1 * S + y1) * S + x0, r111 = (z1 * S + y1) * S + x1;

    float gx1 = fx, gx0 = 1.f - fx;
    float gy1 = fy, gy0 = 1.f - fy;
    float gz1 = fz, gz0 = 1.f - fz;
    // fold attention weight into corner weights (linearity)
    float w000 = gz0 * gy0 * gx0 * awv, w001 = gz0 * gy0 * gx1 * awv;
    float w010 = gz0 * gy1 * gx0 * awv, w011 = gz0 * gy1 * gx1 * awv;
    float w100 = gz1 * gy0 * gx0 * awv, w101 = gz1 * gy0 * gx1 * awv;
    float w110 = gz1 * gy1 * gx0 * awv, w111 = gz1 * gy1 * gx1 * awv;

    if (s < 2) {
        const float* Wvh = Wv + h * HEAD_DIM * C;
        for (int c4 = 0; c4 < C; c4 += 4) {
            float4 u = make_float4(0.f, 0.f, 0.f, 0.f);
            fma4(u, w000, srcT + r000 * C + c4);
            fma4(u, w001, srcT + r001 * C + c4);
            fma4(u, w010, srcT + r010 * C + c4);
            fma4(u, w011, srcT + r011 * C + c4);
            fma4(u, w100, srcT + r100 * C + c4);
            fma4(u, w101, srcT + r101 * C + c4);
            fma4(u, w110, srcT + r110 * C + c4);
            fma4(u, w111, srcT + r111 * C + c4);
#pragma unroll
            for (int j = 0; j < HEAD_DIM; j++) {
                float4 wv4 = ld4(Wvh + j * C + c4);
                acc[j] = fmaf(wv4.x, u.x, fmaf(wv4.y, u.y, fmaf(wv4.z, u.z, fmaf(wv4.w, u.w, acc[j]))));
            }
        }
    } else {
        const float* base = srcT + h * HEAD_DIM;
#pragma unroll
        for (int j4 = 0; j4 < HEAD_DIM; j4 += 4) {
            float4 u = make_float4(0.f, 0.f, 0.f, 0.f);
            fma4(u, w000, base + r000 * HIDDEN + j4);
            fma4(u, w001, base + r001 * HIDDEN + j4);
            fma4(u, w010, base + r010 * HIDDEN + j4);
            fma4(u, w011, base + r011 * HIDDEN + j4);
            fma4(u, w100, base + r100 * HIDDEN + j4);
            fma4(u, w101, base + r101 * HIDDEN + j4);
            fma4(u, w110, base + r110 * HIDDEN + j4);
            fma4(u, w111, base + r111 * HIDDEN + j4);
            acc[j4 + 0] += u.x; acc[j4 + 1] += u.y; acc[j4 + 2] += u.z; acc[j4 + 3] += u.w;
        }
    }
    float* ab = accb + (size_t)sp * HIDDEN * N_Q;
#pragma unroll
    for (int j = 0; j < HEAD_DIM; j++) ab[(h * HEAD_DIM + j) * N_Q + n] = acc[j];
}

// accsum[i] = sum over the 16 (s,p) slices  (float4-vectorized)
__global__ __launch_bounds__(256)
void accsum_kernel(const float* __restrict__ accb, float* __restrict__ accsum)
{
    int i = blockIdx.x * 256 + threadIdx.x;   // float4 index over 192*4096/4
    const int SB4 = HIDDEN * N_Q / 4;
    const float4* src = (const float4*)accb;
    float4 a = src[i];
#pragma unroll
    for (int sp = 1; sp < 16; sp++) {
        float4 b = src[sp * SB4 + i];
        a.x += b.x; a.y += b.y; a.z += b.z; a.w += b.w;
    }
    ((float4*)accsum)[i] = a;
}

// out[o,n] = sum_c Wout[o,c] * accsum[c,n]
__global__ __launch_bounds__(256)
void outconv_kernel(const float* __restrict__ Wout, const float* __restrict__ accsum,
                    float* __restrict__ out)
{
    __shared__ float Wl[8][HIDDEN];
    int tid = threadIdx.x;
    int og = blockIdx.y;
    for (int k = tid; k < 8 * HIDDEN; k += 256) Wl[k / HIDDEN][k % HIDDEN] = Wout[og * 8 * HIDDEN + k];
    __syncthreads();
    int n = blockIdx.x * 256 + tid;
    float acc[8];
#pragma unroll
    for (int i = 0; i < 8; i++) acc[i] = 0.f;
    for (int c = 0; c < HIDDEN; c++) {
        float xv = accsum[c * N_Q + n];
#pragma unroll
        for (int i = 0; i < 8; i++) acc[i] = fmaf(Wl[i][c], xv, acc[i]);
    }
#pragma unroll
    for (int i = 0; i < 8; i++) out[(og * 8 + i) * N_Q + n] = acc[i];
}

// InstanceNorm3d per channel (in-place on d_out)
__global__ __launch_bounds__(256)
void inorm_kernel(float* __restrict__ out, const float* __restrict__ gamma,
                  const float* __restrict__ beta)
{
    int o = blockIdx.x;
    int tid = threadIdx.x;
    float s = 0.f, s2 = 0.f;
    for (int n = tid; n < N_Q; n += 256) {
        float v = out[o * N_Q + n];
        s += v; s2 += v * v;
    }
    __shared__ float rs[256], rs2[256];
    rs[tid] = s; rs2[tid] = s2;
    __syncthreads();
    for (int k = 128; k > 0; k >>= 1) {
        if (tid < k) { rs[tid] += rs[tid + k]; rs2[tid] += rs2[tid + k]; }
        __syncthreads();
    }
    float mu = rs[0] * (1.0f / N_Q);
    float var = rs2[0] * (1.0f / N_Q) - mu * mu;
    float rstd = rsqrtf(var + 1e-5f);
    float g = gamma[o] * rstd;
    float b = beta[o] - mu * g;
    for (int n = tid; n < N_Q; n += 256) {
        out[o * N_Q + n] = fmaf(out[o * N_Q + n], g, b);
    }
}

extern "C" void kernel_launch(void* const* d_in, const int* in_sizes, int n_in,
                              void* d_out, int out_size, void* d_ws, size_t ws_size,
                              hipStream_t stream)
{
    const float* qf    = (const float*)d_in[0];
    const float* v0    = (const float*)d_in[1];
    const float* v1    = (const float*)d_in[2];
    const float* v2    = (const float*)d_in[3];
    const float* v3    = (const float*)d_in[4];
    const float* Wq    = (const float*)d_in[5];
    const float* Wv0   = (const float*)d_in[6];
    const float* Wv1   = (const float*)d_in[7];
    const float* Wv2   = (const float*)d_in[8];
    const float* Wv3   = (const float*)d_in[9];
    const float* Woff  = (const float*)d_in[10];
    const float* boff  = (const float*)d_in[11];
    const float* Wwt   = (const float*)d_in[12];
    const float* bwt   = (const float*)d_in[13];
    const float* Wout  = (const float*)d_in[14];
    const float* gamma = (const float*)d_in[15];
    const float* beta  = (const float*)d_in[16];
    float* out = (float*)d_out;

    float* ws     = (float*)d_ws;
    float* q      = ws;                        // 192*4096     = 786432
    float* offb   = q      + 786432;           // 384*4096     = 1572864
    float* awb    = offb   + 1572864;          // 128*4096     = 524288
    float* v0T    = awb    + 524288;           // 262144*32    = 8388608
    float* v1T    = v0T    + 8388608;          // 32768*64     = 2097152
    float* val2T  = v1T    + 2097152;          // 4096*192     = 786432
    float* val3T  = val2T  + 786432;           // 512*192      = 98304
    float* accb   = val3T  + 98304;            // 16*192*4096  = 12582912
    float* accsum = accb   + 12582912;         // 192*4096     = 786432
    // total ~27.6M floats (~110 MB)

    // q = Wq @ qf
    conv1x1_kernel<128, 16, 0><<<dim3(16, 12), 256, 0, stream>>>(Wq, nullptr, qf, q);
    // offsets = tanh(Woff @ q + boff) * 0.35
    conv1x1_kernel<192, 24, 1><<<dim3(16, 16), 256, 0, stream>>>(Woff, boff, q, offb);
    // attention weights (softmax over 16 per head)
    aw_kernel<<<64, 512, 0, stream>>>(Wwt, bwt, q, awb);
    // spatial-major transposes of big value grids
    transpose_kernel<32, 256><<<1024, 256, 0, stream>>>(v0, v0T, 262144);
    transpose_kernel<64, 128><<<256, 256, 0, stream>>>(v1, v1T, 32768);
    // precomputed value conv for small scales (transposed layout)
    valT_kernel<<<dim3(64, 48), 256, 0, stream>>>(Wv2, v2, val2T, 128, 4096);
    valT_kernel<<<dim3(8, 48), 256, 0, stream>>>(Wv3, v3, val3T, 256, 512);
    // deformable sampling — one (scale,point) per block for 4x occupancy
    sample_kernel<<<dim3(16, 8, 16), 256, 0, stream>>>(offb, awb, v0T, v1T, val2T, val3T,
                                                       Wv0, Wv1, accb);
    // reduce the 16 (s,p) slices
    accsum_kernel<<<768, 256, 0, stream>>>(accb, accsum);
    // final 1x1 conv
    outconv_kernel<<<dim3(16, 16), 256, 0, stream>>>(Wout, accsum, out);
    // instance norm in-place
    inorm_kernel<<<128, 256, 0, stream>>>(out, gamma, beta);
}

// Round 5
// 666.687 us; speedup vs baseline: 1.1780x; 1.1064x over previous
//
#include <hip/hip_runtime.h>
#include <hip/hip_fp16.h>
#include <cmath>

#define N_Q 4096
#define HEADS 8
#define HEAD_DIM 24
#define HIDDEN 192

__device__ __forceinline__ float4 ld4(const float* p) { return *(const float4*)p; }

// accumulate u[0..7] += w * fp16x8 at p (16B aligned)
__device__ __forceinline__ void fma8h(float* u, float w, const __half* p) {
    uint4 raw = *(const uint4*)p;
    const __half2* h2 = reinterpret_cast<const __half2*>(&raw);
#pragma unroll
    for (int k = 0; k < 4; k++) {
        float2 f = __half22float2(h2[k]);
        u[2 * k]     = fmaf(w, f.x, u[2 * k]);
        u[2 * k + 1] = fmaf(w, f.y, u[2 * k + 1]);
    }
}

// acc[0..23] += w * fp16x24 at p (p 16B aligned: head offsets are 48B multiples)
__device__ __forceinline__ void corner24(float* acc, float w, const __half* p) {
    fma8h(acc,      w, p);
    fma8h(acc + 8,  w, p + 8);
    fma8h(acc + 16, w, p + 16);
}

// y[o, n] = sum_c W[o,c] * x[c,n]  (+ optional bias + tanh*0.35 for MODE 1)
template<int K, int OG, int MODE>
__global__ __launch_bounds__(256)
void conv1x1_kernel(const float* __restrict__ W, const float* __restrict__ bias,
                    const float* __restrict__ x, float* __restrict__ y)
{
    __shared__ float Wl[OG][K];
    int tid = threadIdx.x;
    int og = blockIdx.y;
    for (int k = tid; k < OG * K; k += 256) Wl[k / K][k % K] = W[og * OG * K + k];
    __syncthreads();
    int n = blockIdx.x * 256 + tid;
    float acc[OG];
#pragma unroll
    for (int i = 0; i < OG; i++) acc[i] = 0.f;
    for (int c = 0; c < K; c++) {
        float xv = x[c * N_Q + n];
#pragma unroll
        for (int i = 0; i < OG; i++) acc[i] = fmaf(Wl[i][c], xv, acc[i]);
    }
#pragma unroll
    for (int i = 0; i < OG; i++) {
        int o = og * OG + i;
        float r = acc[i];
        if constexpr (MODE == 1) r = tanhf(r + bias[o]) * 0.35f;
        y[o * N_Q + n] = r;
    }
}

// attention weights: logits = Wwt·q + bwt, softmax over the 16 (s,p) rows per head
__global__ __launch_bounds__(512)
void aw_kernel(const float* __restrict__ Wwt, const float* __restrict__ bwt,
               const float* __restrict__ q, float* __restrict__ aw)
{
    int tid = threadIdx.x;
    int h = tid >> 6;          // one wave per head
    int lane = tid & 63;
    int n = blockIdx.x * 64 + lane;
    float acc[16];
#pragma unroll
    for (int i = 0; i < 16; i++) acc[i] = bwt[h * 16 + i];
    for (int c = 0; c < 192; c++) {
        float qv = q[c * N_Q + n];
#pragma unroll
        for (int i = 0; i < 16; i++) acc[i] = fmaf(Wwt[(h * 16 + i) * 192 + c], qv, acc[i]);
    }
    float m = acc[0];
#pragma unroll
    for (int i = 1; i < 16; i++) m = fmaxf(m, acc[i]);
    float s = 0.f;
#pragma unroll
    for (int i = 0; i < 16; i++) { acc[i] = __expf(acc[i] - m); s += acc[i]; }
    float inv = 1.0f / s;
#pragma unroll
    for (int i = 0; i < 16; i++) aw[(h * 16 + i) * N_Q + n] = acc[i] * inv;
}

// [C, Nv] f32 -> [Nv, C] fp16 via LDS tile (coalesced both sides)
template<int C, int P>
__global__ __launch_bounds__(256)
void transpose_h_kernel(const float* __restrict__ src, __half* __restrict__ dst, int Nv)
{
    __shared__ float lds[P][C + 1];
    int tid = threadIdx.x;
    int pos0 = blockIdx.x * P;
    for (int k = tid; k < P * C; k += 256) {
        int c = k / P, p = k % P;
        lds[p][c] = src[c * Nv + pos0 + p];
    }
    __syncthreads();
    for (int k = tid; k < P * C; k += 256) {
        int p = k / C, c = k % C;
        dst[(pos0 + p) * C + c] = __float2half(lds[p][c]);
    }
}

// valT[pos][192] fp16 = Wv(192xC) @ v(C x Nv) for a 64-pos tile.
// v loaded coalesced into LDS (acts as the transpose); Wv rows are wave-uniform
// -> scalar loads; each thread keeps 48 accumulators (one o-range per wave).
template<int C>
__global__ __launch_bounds__(256)
void valconv_kernel(const float* __restrict__ Wv, const float* __restrict__ v,
                    __half* __restrict__ valT, int Nv)
{
    __shared__ float ldsv[C * 64];
    __shared__ __half ldsout[64 * 194];   // pad 194 -> bank-stride 1 on write
    int tid = threadIdx.x;
    int p0 = blockIdx.x * 64;
    for (int k = tid; k < C * 64; k += 256) {
        int c = k >> 6, p = k & 63;
        ldsv[c * 64 + p] = v[c * Nv + p0 + p];   // coalesced 64-wide
    }
    __syncthreads();

    int w = __builtin_amdgcn_readfirstlane(tid >> 6);  // wave id 0..3
    int lane = tid & 63;                                // = p
    const float* Wrow = Wv + (w * 48) * C;              // rows w*48 .. w*48+47

    float acc[48];
#pragma unroll
    for (int k = 0; k < 48; k++) acc[k] = 0.f;
    for (int c = 0; c < C; c++) {
        float vv = ldsv[c * 64 + lane];
#pragma unroll
        for (int k = 0; k < 48; k++)
            acc[k] = fmaf(Wrow[k * C + c], vv, acc[k]);   // scalar (uniform) weight
    }
#pragma unroll
    for (int k = 0; k < 48; k++)
        ldsout[lane * 194 + w * 48 + k] = __float2half(acc[k]);
    __syncthreads();

    // coalesced fp16 write: 64 rows x 96 uints
    const unsigned int* lo = (const unsigned int*)ldsout;
    unsigned int* dst = (unsigned int*)valT;
    for (int k = tid; k < 64 * 96; k += 256) {
        int p = k / 96, i = k % 96;
        dst[(size_t)(p0 + p) * 96 + i] = lo[p * 97 + i];
    }
}

// main deformable sampling; blockIdx = (n-tile, head, s*4+p) — one point per block
// s=0: fused conv (interpolate 32 raw fp16 channels, apply head's 24x32 block —
//      weights read via uniform/scalar loads)
// s>=1: gather 24 precomputed fp16 head-channels per corner
__global__ __launch_bounds__(256)
void sample_kernel(const float* __restrict__ offb, const float* __restrict__ awb,
                   const __half* __restrict__ v0T, const __half* __restrict__ val1T,
                   const __half* __restrict__ val2T, const __half* __restrict__ val3T,
                   const float* __restrict__ Wv0,
                   float* __restrict__ accb)
{
    int tid = threadIdx.x;
    int n = blockIdx.x * 256 + tid;
    int h = blockIdx.y;
    int sp = blockIdx.z;
    int s = sp >> 2, p = sp & 3;

    int wx = n & 15, hy = (n >> 4) & 15, dz = n >> 8;
    const float step = 2.0f / 15.0f;
    float bx = -1.f + wx * step;
    float by = -1.f + hy * step;
    float bz = -1.f + dz * step;

    float acc[HEAD_DIM];
#pragma unroll
    for (int j = 0; j < HEAD_DIM; j++) acc[j] = 0.f;

    int S = 64;
    const __half* srcT = v0T;
    if (s == 1)      { S = 32; srcT = val1T; }
    else if (s == 2) { S = 16; srcT = val2T; }
    else if (s == 3) { S = 8;  srcT = val3T; }
    float fS = (float)S;

    int orow = ((h * 4 + s) * 4 + p) * 3;
    float ox = offb[(orow + 0) * N_Q + n];
    float oy = offb[(orow + 1) * N_Q + n];
    float oz = offb[(orow + 2) * N_Q + n];
    float awv = awb[(h * 16 + s * 4 + p) * N_Q + n];

    float ix = fminf(fmaxf(((bx + ox + 1.f) * fS - 1.f) * 0.5f, 0.f), fS - 1.f);
    float iy = fminf(fmaxf(((by + oy + 1.f) * fS - 1.f) * 0.5f, 0.f), fS - 1.f);
    float iz = fminf(fmaxf(((bz + oz + 1.f) * fS - 1.f) * 0.5f, 0.f), fS - 1.f);

    float x0f = floorf(ix), y0f = floorf(iy), z0f = floorf(iz);
    float fx = ix - x0f, fy = iy - y0f, fz = iz - z0f;
    int x0 = (int)x0f, y0 = (int)y0f, z0 = (int)z0f;
    int x1 = min(x0 + 1, S - 1), y1 = min(y0 + 1, S - 1), z1 = min(z0 + 1, S - 1);

    int r000 = (z0 * S + y0) * S + x0, r001 = (z0 * S + y0) * S + x1;
    int r010 = (z0 * S + y1) * S + x0, r011 = (z0 * S + y1) * S + x1;
    int r100 = (z1 * S + y0) * S + x0, r101 = (z1 * S + y0) * S + x1;
    int r110 = (z1 * S + y1) * S + x0, r111 = (z1 * S + y1) * S + x1;

    float gx1 = fx, gx0 = 1.f - fx;
    float gy1 = fy, gy0 = 1.f - fy;
    float gz1 = fz, gz0 = 1.f - fz;
    // fold attention weight into corner weights (linearity)
    float w000 = gz0 * gy0 * gx0 * awv, w001 = gz0 * gy0 * gx1 * awv;
    float w010 = gz0 * gy1 * gx0 * awv, w011 = gz0 * gy1 * gx1 * awv;
    float w100 = gz1 * gy0 * gx0 * awv, w101 = gz1 * gy0 * gx1 * awv;
    float w110 = gz1 * gy1 * gx0 * awv, w111 = gz1 * gy1 * gx1 * awv;

    if (s == 0) {
        const float* Wvh = Wv0 + h * HEAD_DIM * 32;   // uniform -> scalar loads
#pragma unroll
        for (int c8 = 0; c8 < 32; c8 += 8) {
            float u[8] = {0.f, 0.f, 0.f, 0.f, 0.f, 0.f, 0.f, 0.f};
            fma8h(u, w000, srcT + r000 * 32 + c8);
            fma8h(u, w001, srcT + r001 * 32 + c8);
            fma8h(u, w010, srcT + r010 * 32 + c8);
            fma8h(u, w011, srcT + r011 * 32 + c8);
            fma8h(u, w100, srcT + r100 * 32 + c8);
            fma8h(u, w101, srcT + r101 * 32 + c8);
            fma8h(u, w110, srcT + r110 * 32 + c8);
            fma8h(u, w111, srcT + r111 * 32 + c8);
#pragma unroll
            for (int j = 0; j < HEAD_DIM; j++) {
                const float* wp = Wvh + j * 32 + c8;
                float4 wa = ld4(wp), wb = ld4(wp + 4);
                acc[j] = fmaf(wa.x, u[0], fmaf(wa.y, u[1], fmaf(wa.z, u[2], fmaf(wa.w, u[3],
                         fmaf(wb.x, u[4], fmaf(wb.y, u[5], fmaf(wb.z, u[6], fmaf(wb.w, u[7], acc[j]))))))));
            }
        }
    } else {
        const __half* base = srcT + h * HEAD_DIM;     // 48B-multiple offset, 16B aligned
        corner24(acc, w000, base + (size_t)r000 * HIDDEN);
        corner24(acc, w001, base + (size_t)r001 * HIDDEN);
        corner24(acc, w010, base + (size_t)r010 * HIDDEN);
        corner24(acc, w011, base + (size_t)r011 * HIDDEN);
        corner24(acc, w100, base + (size_t)r100 * HIDDEN);
        corner24(acc, w101, base + (size_t)r101 * HIDDEN);
        corner24(acc, w110, base + (size_t)r110 * HIDDEN);
        corner24(acc, w111, base + (size_t)r111 * HIDDEN);
    }

    float* ab = accb + (size_t)sp * HIDDEN * N_Q;
#pragma unroll
    for (int j = 0; j < HEAD_DIM; j++) ab[(h * HEAD_DIM + j) * N_Q + n] = acc[j];
}

// accsum[i] = sum over the 16 (s,p) slices  (float4-vectorized)
__global__ __launch_bounds__(256)
void accsum_kernel(const float* __restrict__ accb, float* __restrict__ accsum)
{
    int i = blockIdx.x * 256 + threadIdx.x;   // float4 index over 192*4096/4
    const int SB4 = HIDDEN * N_Q / 4;
    const float4* src = (const float4*)accb;
    float4 a = src[i];
#pragma unroll
    for (int sp = 1; sp < 16; sp++) {
        float4 b = src[sp * SB4 + i];
        a.x += b.x; a.y += b.y; a.z += b.z; a.w += b.w;
    }
    ((float4*)accsum)[i] = a;
}

// out[o,n] = sum_c Wout[o,c] * accsum[c,n]
__global__ __launch_bounds__(256)
void outconv_kernel(const float* __restrict__ Wout, const float* __restrict__ accsum,
                    float* __restrict__ out)
{
    __shared__ float Wl[16][HIDDEN];
    int tid = threadIdx.x;
    int og = blockIdx.y;
    for (int k = tid; k < 16 * HIDDEN; k += 256) Wl[k / HIDDEN][k % HIDDEN] = Wout[og * 16 * HIDDEN + k];
    __syncthreads();
    int n = blockIdx.x * 256 + tid;
    float acc[16];
#pragma unroll
    for (int i = 0; i < 16; i++) acc[i] = 0.f;
    for (int c = 0; c < HIDDEN; c++) {
        float xv = accsum[c * N_Q + n];
#pragma unroll
        for (int i = 0; i < 16; i++) acc[i] = fmaf(Wl[i][c], xv, acc[i]);
    }
#pragma unroll
    for (int i = 0; i < 16; i++) out[(og * 16 + i) * N_Q + n] = acc[i];
}

// InstanceNorm3d per channel (in-place on d_out)
__global__ __launch_bounds__(256)
void inorm_kernel(float* __restrict__ out, const float* __restrict__ gamma,
                  const float* __restrict__ beta)
{
    int o = blockIdx.x;
    int tid = threadIdx.x;
    float s = 0.f, s2 = 0.f;
    for (int n = tid; n < N_Q; n += 256) {
        float v = out[o * N_Q + n];
        s += v; s2 += v * v;
    }
    __shared__ float rs[256], rs2[256];
    rs[tid] = s; rs2[tid] = s2;
    __syncthreads();
    for (int k = 128; k > 0; k >>= 1) {
        if (tid < k) { rs[tid] += rs[tid + k]; rs2[tid] += rs2[tid + k]; }
        __syncthreads();
    }
    float mu = rs[0] * (1.0f / N_Q);
    float var = rs2[0] * (1.0f / N_Q) - mu * mu;
    float rstd = rsqrtf(var + 1e-5f);
    float g = gamma[o] * rstd;
    float b = beta[o] - mu * g;
    for (int n = tid; n < N_Q; n += 256) {
        out[o * N_Q + n] = fmaf(out[o * N_Q + n], g, b);
    }
}

extern "C" void kernel_launch(void* const* d_in, const int* in_sizes, int n_in,
                              void* d_out, int out_size, void* d_ws, size_t ws_size,
                              hipStream_t stream)
{
    const float* qf    = (const float*)d_in[0];
    const float* v0    = (const float*)d_in[1];
    const float* v1    = (const float*)d_in[2];
    const float* v2    = (const float*)d_in[3];
    const float* v3    = (const float*)d_in[4];
    const float* Wq    = (const float*)d_in[5];
    const float* Wv0   = (const float*)d_in[6];
    const float* Wv1   = (const float*)d_in[7];
    const float* Wv2   = (const float*)d_in[8];
    const float* Wv3   = (const float*)d_in[9];
    const float* Woff  = (const float*)d_in[10];
    const float* boff  = (const float*)d_in[11];
    const float* Wwt   = (const float*)d_in[12];
    const float* bwt   = (const float*)d_in[13];
    const float* Wout  = (const float*)d_in[14];
    const float* gamma = (const float*)d_in[15];
    const float* beta  = (const float*)d_in[16];
    float* out = (float*)d_out;

    float* ws     = (float*)d_ws;
    float*  q      = ws;                        // 786432 f
    float*  offb   = q      + 786432;           // 1572864 f
    float*  awb    = offb   + 1572864;          // 524288 f
    __half* v0T    = (__half*)(awb + 524288);   // 262144*32 h  (4194304 f)
    __half* val1T  = (__half*)((float*)v0T + 4194304);  // 32768*192 h (3145728 f)
    __half* val2T  = (__half*)((float*)val1T + 3145728); // 4096*192 h (393216 f)
    __half* val3T  = (__half*)((float*)val2T + 393216);  // 512*192 h (49152 f)
    float*  accb   = (float*)val3T + 49152;     // 16*786432 f
    float*  accsum = accb   + 12582912;         // 786432 f
    // total ~24.0M floats (~96 MB)

    // q = Wq @ qf
    conv1x1_kernel<128, 16, 0><<<dim3(16, 12), 256, 0, stream>>>(Wq, nullptr, qf, q);
    // offsets = tanh(Woff @ q + boff) * 0.35
    conv1x1_kernel<192, 24, 1><<<dim3(16, 16), 256, 0, stream>>>(Woff, boff, q, offb);
    // attention weights (softmax over 16 per head)
    aw_kernel<<<64, 512, 0, stream>>>(Wwt, bwt, q, awb);
    // v0 -> spatial-major fp16 (raw channels; conv fused into sampling)
    transpose_h_kernel<32, 256><<<1024, 256, 0, stream>>>(v0, v0T, 262144);
    // precomputed value convs (fp16, pos-major) for s=1,2,3
    valconv_kernel<64><<<512, 256, 0, stream>>>(Wv1, v1, val1T, 32768);
    valconv_kernel<128><<<64, 256, 0, stream>>>(Wv2, v2, val2T, 4096);
    valconv_kernel<256><<<8, 256, 0, stream>>>(Wv3, v3, val3T, 512);
    // deformable sampling — one (scale,point) per block
    sample_kernel<<<dim3(16, 8, 16), 256, 0, stream>>>(offb, awb, v0T, val1T, val2T, val3T,
                                                       Wv0, accb);
    // reduce the 16 (s,p) slices
    accsum_kernel<<<768, 256, 0, stream>>>(accb, accsum);
    // final 1x1 conv
    outconv_kernel<<<dim3(16, 8), 256, 0, stream>>>(Wout, accsum, out);
    // instance norm in-place
    inorm_kernel<<<128, 256, 0, stream>>>(out, gamma, beta);
}

// Round 6
// 479.004 us; speedup vs baseline: 1.6396x; 1.3918x over previous
//
#include <hip/hip_runtime.h>
#include <hip/hip_fp16.h>
#include <cmath>

#define N_Q 4096
#define HEADS 8
#define HEAD_DIM 24
#define HIDDEN 192

__device__ __forceinline__ float4 ld4(const float* p) { return *(const float4*)p; }

// accumulate u[0..7] += w * fp16x8 at p (16B aligned)
__device__ __forceinline__ void fma8h(float* u, float w, const __half* p) {
    uint4 raw = *(const uint4*)p;
    const __half2* h2 = reinterpret_cast<const __half2*>(&raw);
#pragma unroll
    for (int k = 0; k < 4; k++) {
        float2 f = __half22float2(h2[k]);
        u[2 * k]     = fmaf(w, f.x, u[2 * k]);
        u[2 * k + 1] = fmaf(w, f.y, u[2 * k + 1]);
    }
}

// acc[0..23] += w * fp16x24 at p (p 16B aligned: head offsets are 48B multiples)
__device__ __forceinline__ void corner24(float* acc, float w, const __half* p) {
    fma8h(acc,      w, p);
    fma8h(acc + 8,  w, p + 8);
    fma8h(acc + 16, w, p + 16);
}

// y[o, n] = sum_c W[o,c] * x[c,n]
// MODE 0: plain   MODE 1: tanh(.+bias)*0.35   MODE 2: .+bias
template<int K, int OG, int MODE>
__global__ __launch_bounds__(256)
void conv1x1_kernel(const float* __restrict__ W, const float* __restrict__ bias,
                    const float* __restrict__ x, float* __restrict__ y)
{
    __shared__ float Wl[OG][K];
    int tid = threadIdx.x;
    int og = blockIdx.y;
    for (int k = tid; k < OG * K; k += 256) Wl[k / K][k % K] = W[og * OG * K + k];
    __syncthreads();
    int n = blockIdx.x * 256 + tid;
    float acc[OG];
#pragma unroll
    for (int i = 0; i < OG; i++) acc[i] = 0.f;
    for (int c = 0; c < K; c++) {
        float xv = x[c * N_Q + n];
#pragma unroll
        for (int i = 0; i < OG; i++) acc[i] = fmaf(Wl[i][c], xv, acc[i]);
    }
#pragma unroll
    for (int i = 0; i < OG; i++) {
        int o = og * OG + i;
        float r = acc[i];
        if constexpr (MODE == 1) r = tanhf(r + bias[o]) * 0.35f;
        if constexpr (MODE == 2) r = r + bias[o];
        y[o * N_Q + n] = r;
    }
}

// softmax over the 16 (s,p) logit rows per head, in-place; thread per (h,n)
__global__ __launch_bounds__(256)
void softmax16_kernel(float* __restrict__ aw)
{
    int idx = blockIdx.x * 256 + threadIdx.x;   // 0..32767
    int h = idx >> 12;
    int n = idx & 4095;
    float v[16];
    float m = -1e30f;
#pragma unroll
    for (int i = 0; i < 16; i++) { v[i] = aw[(h * 16 + i) * N_Q + n]; m = fmaxf(m, v[i]); }
    float ssum = 0.f;
#pragma unroll
    for (int i = 0; i < 16; i++) { v[i] = __expf(v[i] - m); ssum += v[i]; }
    float inv = 1.0f / ssum;
#pragma unroll
    for (int i = 0; i < 16; i++) aw[(h * 16 + i) * N_Q + n] = v[i] * inv;
}

// [C, Nv] f32 -> [Nv, C] fp16 via LDS tile (coalesced both sides)
template<int C, int P>
__global__ __launch_bounds__(256)
void transpose_h_kernel(const float* __restrict__ src, __half* __restrict__ dst, int Nv)
{
    __shared__ float lds[P][C + 1];
    int tid = threadIdx.x;
    int pos0 = blockIdx.x * P;
    for (int k = tid; k < P * C; k += 256) {
        int c = k / P, p = k % P;
        lds[p][c] = src[c * Nv + pos0 + p];
    }
    __syncthreads();
    for (int k = tid; k < P * C; k += 256) {
        int p = k / C, c = k % C;
        dst[(pos0 + p) * C + c] = __float2half(lds[p][c]);
    }
}

// valT[pos][og0..og0+OG) fp16 = Wv(rows og0..og0+OG) @ v(C x Nv), 64-pos tile.
// Weights staged in LDS (read back as wave-uniform broadcast); v coalesced;
// output staged in LDS for coalesced fp16 stores.
template<int C, int OG>
__global__ __launch_bounds__(256)
void valconv_kernel(const float* __restrict__ Wv, const float* __restrict__ v,
                    __half* __restrict__ valT, int Nv)
{
    __shared__ float Wl[OG][C];
    __shared__ __half outs[64 * OG];
    int tid = threadIdx.x;
    int p0 = blockIdx.x * 64;
    int og0 = blockIdx.y * OG;
    for (int k = tid; k < OG * C; k += 256) Wl[k / C][k % C] = Wv[(size_t)(og0 + k / C) * C + (k % C)];
    __syncthreads();

    int osub = tid >> 6;            // 0..3 (wave id)
    int lane = tid & 63;            // position within tile
    constexpr int PT = OG / 4;      // outputs per thread
    float acc[PT];
#pragma unroll
    for (int i = 0; i < PT; i++) acc[i] = 0.f;
    for (int c = 0; c < C; c++) {
        float vv = v[(size_t)c * Nv + p0 + lane];   // coalesced 64-wide
#pragma unroll
        for (int i = 0; i < PT; i++)
            acc[i] = fmaf(Wl[osub * PT + i][c], vv, acc[i]);  // LDS broadcast
    }
#pragma unroll
    for (int i = 0; i < PT; i++)
        outs[lane * OG + osub * PT + i] = __float2half(acc[i]);
    __syncthreads();

    unsigned int* dst = (unsigned int*)valT;
    const unsigned int* src = (const unsigned int*)outs;
    constexpr int UPP = OG / 2;     // uints per position
    for (int k = tid; k < 64 * UPP; k += 256) {
        int p = k / UPP, i = k % UPP;
        dst[(size_t)(p0 + p) * (HIDDEN / 2) + (og0 / 2) + i] = src[p * UPP + i];
    }
}

// main deformable sampling; blockIdx = (n-tile, head, s*4+p) — one point per block
// s=0: fused conv (interpolate 32 raw fp16 channels, apply head's 24x32 block)
// s>=1: gather 24 precomputed fp16 head-channels per corner
__global__ __launch_bounds__(256)
void sample_kernel(const float* __restrict__ offb, const float* __restrict__ awb,
                   const __half* __restrict__ v0T, const __half* __restrict__ val1T,
                   const __half* __restrict__ val2T, const __half* __restrict__ val3T,
                   const float* __restrict__ Wv0,
                   float* __restrict__ accb)
{
    int tid = threadIdx.x;
    int n = blockIdx.x * 256 + tid;
    int h = blockIdx.y;
    int sp = blockIdx.z;
    int s = sp >> 2, p = sp & 3;

    int wx = n & 15, hy = (n >> 4) & 15, dz = n >> 8;
    const float step = 2.0f / 15.0f;
    float bx = -1.f + wx * step;
    float by = -1.f + hy * step;
    float bz = -1.f + dz * step;

    float acc[HEAD_DIM];
#pragma unroll
    for (int j = 0; j < HEAD_DIM; j++) acc[j] = 0.f;

    int S = 64;
    const __half* srcT = v0T;
    if (s == 1)      { S = 32; srcT = val1T; }
    else if (s == 2) { S = 16; srcT = val2T; }
    else if (s == 3) { S = 8;  srcT = val3T; }
    float fS = (float)S;

    int orow = ((h * 4 + s) * 4 + p) * 3;
    float ox = offb[(orow + 0) * N_Q + n];
    float oy = offb[(orow + 1) * N_Q + n];
    float oz = offb[(orow + 2) * N_Q + n];
    float awv = awb[(h * 16 + s * 4 + p) * N_Q + n];

    float ix = fminf(fmaxf(((bx + ox + 1.f) * fS - 1.f) * 0.5f, 0.f), fS - 1.f);
    float iy = fminf(fmaxf(((by + oy + 1.f) * fS - 1.f) * 0.5f, 0.f), fS - 1.f);
    float iz = fminf(fmaxf(((bz + oz + 1.f) * fS - 1.f) * 0.5f, 0.f), fS - 1.f);

    float x0f = floorf(ix), y0f = floorf(iy), z0f = floorf(iz);
    float fx = ix - x0f, fy = iy - y0f, fz = iz - z0f;
    int x0 = (int)x0f, y0 = (int)y0f, z0 = (int)z0f;
    int x1 = min(x0 + 1, S - 1), y1 = min(y0 + 1, S - 1), z1 = min(z0 + 1, S - 1);

    int r000 = (z0 * S + y0) * S + x0, r001 = (z0 * S + y0) * S + x1;
    int r010 = (z0 * S + y1) * S + x0, r011 = (z0 * S + y1) * S + x1;
    int r100 = (z1 * S + y0) * S + x0, r101 = (z1 * S + y0) * S + x1;
    int r110 = (z1 * S + y1) * S + x0, r111 = (z1 * S + y1) * S + x1;

    float gx1 = fx, gx0 = 1.f - fx;
    float gy1 = fy, gy0 = 1.f - fy;
    float gz1 = fz, gz0 = 1.f - fz;
    float w000 = gz0 * gy0 * gx0 * awv, w001 = gz0 * gy0 * gx1 * awv;
    float w010 = gz0 * gy1 * gx0 * awv, w011 = gz0 * gy1 * gx1 * awv;
    float w100 = gz1 * gy0 * gx0 * awv, w101 = gz1 * gy0 * gx1 * awv;
    float w110 = gz1 * gy1 * gx0 * awv, w111 = gz1 * gy1 * gx1 * awv;

    if (s == 0) {
        const float* Wvh = Wv0 + h * HEAD_DIM * 32;   // uniform -> scalar loads
#pragma unroll
        for (int c8 = 0; c8 < 32; c8 += 8) {
            float u[8] = {0.f, 0.f, 0.f, 0.f, 0.f, 0.f, 0.f, 0.f};
            fma8h(u, w000, srcT + r000 * 32 + c8);
            fma8h(u, w001, srcT + r001 * 32 + c8);
            fma8h(u, w010, srcT + r010 * 32 + c8);
            fma8h(u, w011, srcT + r011 * 32 + c8);
            fma8h(u, w100, srcT + r100 * 32 + c8);
            fma8h(u, w101, srcT + r101 * 32 + c8);
            fma8h(u, w110, srcT + r110 * 32 + c8);
            fma8h(u, w111, srcT + r111 * 32 + c8);
#pragma unroll
            for (int j = 0; j < HEAD_DIM; j++) {
                const float* wp = Wvh + j * 32 + c8;
                float4 wa = ld4(wp), wb = ld4(wp + 4);
                acc[j] = fmaf(wa.x, u[0], fmaf(wa.y, u[1], fmaf(wa.z, u[2], fmaf(wa.w, u[3],
                         fmaf(wb.x, u[4], fmaf(wb.y, u[5], fmaf(wb.z, u[6], fmaf(wb.w, u[7], acc[j]))))))));
            }
        }
    } else {
        const __half* base = srcT + h * HEAD_DIM;
        corner24(acc, w000, base + (size_t)r000 * HIDDEN);
        corner24(acc, w001, base + (size_t)r001 * HIDDEN);
        corner24(acc, w010, base + (size_t)r010 * HIDDEN);
        corner24(acc, w011, base + (size_t)r011 * HIDDEN);
        corner24(acc, w100, base + (size_t)r100 * HIDDEN);
        corner24(acc, w101, base + (size_t)r101 * HIDDEN);
        corner24(acc, w110, base + (size_t)r110 * HIDDEN);
        corner24(acc, w111, base + (size_t)r111 * HIDDEN);
    }

    float* ab = accb + (size_t)sp * HIDDEN * N_Q;
#pragma unroll
    for (int j = 0; j < HEAD_DIM; j++) ab[(h * HEAD_DIM + j) * N_Q + n] = acc[j];
}

// accsum[i] = sum over the 16 (s,p) slices  (float4-vectorized)
__global__ __launch_bounds__(256)
void accsum_kernel(const float* __restrict__ accb, float* __restrict__ accsum)
{
    int i = blockIdx.x * 256 + threadIdx.x;
    const int SB4 = HIDDEN * N_Q / 4;
    const float4* src = (const float4*)accb;
    float4 a = src[i];
#pragma unroll
    for (int sp = 1; sp < 16; sp++) {
        float4 b = src[sp * SB4 + i];
        a.x += b.x; a.y += b.y; a.z += b.z; a.w += b.w;
    }
    ((float4*)accsum)[i] = a;
}

// out[o,n] = sum_c Wout[o,c] * accsum[c,n]
__global__ __launch_bounds__(256)
void outconv_kernel(const float* __restrict__ Wout, const float* __restrict__ accsum,
                    float* __restrict__ out)
{
    __shared__ float Wl[16][HIDDEN];
    int tid = threadIdx.x;
    int og = blockIdx.y;
    for (int k = tid; k < 16 * HIDDEN; k += 256) Wl[k / HIDDEN][k % HIDDEN] = Wout[og * 16 * HIDDEN + k];
    __syncthreads();
    int n = blockIdx.x * 256 + tid;
    float acc[16];
#pragma unroll
    for (int i = 0; i < 16; i++) acc[i] = 0.f;
    for (int c = 0; c < HIDDEN; c++) {
        float xv = accsum[c * N_Q + n];
#pragma unroll
        for (int i = 0; i < 16; i++) acc[i] = fmaf(Wl[i][c], xv, acc[i]);
    }
#pragma unroll
    for (int i = 0; i < 16; i++) out[(og * 16 + i) * N_Q + n] = acc[i];
}

// InstanceNorm3d per channel (in-place on d_out)
__global__ __launch_bounds__(256)
void inorm_kernel(float* __restrict__ out, const float* __restrict__ gamma,
                  const float* __restrict__ beta)
{
    int o = blockIdx.x;
    int tid = threadIdx.x;
    float s = 0.f, s2 = 0.f;
    for (int n = tid; n < N_Q; n += 256) {
        float v = out[o * N_Q + n];
        s += v; s2 += v * v;
    }
    __shared__ float rs[256], rs2[256];
    rs[tid] = s; rs2[tid] = s2;
    __syncthreads();
    for (int k = 128; k > 0; k >>= 1) {
        if (tid < k) { rs[tid] += rs[tid + k]; rs2[tid] += rs2[tid + k]; }
        __syncthreads();
    }
    float mu = rs[0] * (1.0f / N_Q);
    float var = rs2[0] * (1.0f / N_Q) - mu * mu;
    float rstd = rsqrtf(var + 1e-5f);
    float g = gamma[o] * rstd;
    float b = beta[o] - mu * g;
    for (int n = tid; n < N_Q; n += 256) {
        out[o * N_Q + n] = fmaf(out[o * N_Q + n], g, b);
    }
}

extern "C" void kernel_launch(void* const* d_in, const int* in_sizes, int n_in,
                              void* d_out, int out_size, void* d_ws, size_t ws_size,
                              hipStream_t stream)
{
    const float* qf    = (const float*)d_in[0];
    const float* v0    = (const float*)d_in[1];
    const float* v1    = (const float*)d_in[2];
    const float* v2    = (const float*)d_in[3];
    const float* v3    = (const float*)d_in[4];
    const float* Wq    = (const float*)d_in[5];
    const float* Wv0   = (const float*)d_in[6];
    const float* Wv1   = (const float*)d_in[7];
    const float* Wv2   = (const float*)d_in[8];
    const float* Wv3   = (const float*)d_in[9];
    const float* Woff  = (const float*)d_in[10];
    const float* boff  = (const float*)d_in[11];
    const float* Wwt   = (const float*)d_in[12];
    const float* bwt   = (const float*)d_in[13];
    const float* Wout  = (const float*)d_in[14];
    const float* gamma = (const float*)d_in[15];
    const float* beta  = (const float*)d_in[16];
    float* out = (float*)d_out;

    float* ws     = (float*)d_ws;
    float*  q      = ws;                        // 786432 f
    float*  offb   = q      + 786432;           // 1572864 f
    float*  awb    = offb   + 1572864;          // 524288 f  (logits then softmax in-place)
    __half* v0T    = (__half*)(awb + 524288);   // 262144*32 h  (4194304 f)
    __half* val1T  = (__half*)((float*)v0T + 4194304);   // 32768*192 h (3145728 f)
    __half* val2T  = (__half*)((float*)val1T + 3145728); // 4096*192 h (393216 f)
    __half* val3T  = (__half*)((float*)val2T + 393216);  // 512*192 h (49152 f)
    float*  accb   = (float*)val3T + 49152;     // 16*786432 f
    float*  accsum = accb   + 12582912;         // 786432 f

    // q = Wq @ qf
    conv1x1_kernel<128, 16, 0><<<dim3(16, 12), 256, 0, stream>>>(Wq, nullptr, qf, q);
    // offsets = tanh(Woff @ q + boff) * 0.35
    conv1x1_kernel<192, 24, 1><<<dim3(16, 16), 256, 0, stream>>>(Woff, boff, q, offb);
    // attention logits (+bias), then softmax over 16 per head (in-place)
    conv1x1_kernel<192, 16, 2><<<dim3(16, 8), 256, 0, stream>>>(Wwt, bwt, q, awb);
    softmax16_kernel<<<128, 256, 0, stream>>>(awb);
    // v0 -> spatial-major fp16 (raw channels; conv fused into sampling)
    transpose_h_kernel<32, 256><<<1024, 256, 0, stream>>>(v0, v0T, 262144);
    // precomputed value convs (fp16, pos-major) for s=1,2,3
    valconv_kernel<64, 24><<<dim3(512, 8), 256, 0, stream>>>(Wv1, v1, val1T, 32768);
    valconv_kernel<128, 12><<<dim3(64, 16), 256, 0, stream>>>(Wv2, v2, val2T, 4096);
    valconv_kernel<256, 8><<<dim3(8, 24), 256, 0, stream>>>(Wv3, v3, val3T, 512);
    // deformable sampling — one (scale,point) per block
    sample_kernel<<<dim3(16, 8, 16), 256, 0, stream>>>(offb, awb, v0T, val1T, val2T, val3T,
                                                       Wv0, accb);
    // reduce the 16 (s,p) slices
    accsum_kernel<<<768, 256, 0, stream>>>(accb, accsum);
    // final 1x1 conv
    outconv_kernel<<<dim3(16, 8), 256, 0, stream>>>(Wout, accsum, out);
    // instance norm in-place
    inorm_kernel<<<128, 256, 0, stream>>>(out, gamma, beta);
}

// Round 7
// 312.768 us; speedup vs baseline: 2.5110x; 1.5315x over previous
//
#include <hip/hip_runtime.h>
#include <hip/hip_fp16.h>
#include <cmath>

#define N_Q 4096
#define HEADS 8
#define HEAD_DIM 24
#define HIDDEN 192

__device__ __forceinline__ float4 ld4(const float* p) { return *(const float4*)p; }

// accumulate u[0..7] += w * fp16x8 at p (16B aligned)
__device__ __forceinline__ void fma8h(float* u, float w, const __half* p) {
    uint4 raw = *(const uint4*)p;
    const __half2* h2 = reinterpret_cast<const __half2*>(&raw);
#pragma unroll
    for (int k = 0; k < 4; k++) {
        float2 f = __half22float2(h2[k]);
        u[2 * k]     = fmaf(w, f.x, u[2 * k]);
        u[2 * k + 1] = fmaf(w, f.y, u[2 * k + 1]);
    }
}

// acc[0..23] += w * fp16x24 at p (p 16B aligned: head offsets are 48B multiples)
__device__ __forceinline__ void corner24(float* acc, float w, const __half* p) {
    fma8h(acc,      w, p);
    fma8h(acc + 8,  w, p + 8);
    fma8h(acc + 16, w, p + 16);
}

// Wcomb[o][c] (512x128) = concat(Woff,Wwt)[o][k] @ Wq[k][c]  (K=192)
__global__ __launch_bounds__(256)
void wcomb_kernel(const float* __restrict__ Woff, const float* __restrict__ Wwt,
                  const float* __restrict__ Wq, float* __restrict__ Wcomb)
{
    int o = blockIdx.x * 2 + (threadIdx.x >> 7);
    int c = threadIdx.x & 127;
    const float* A = (o < 384) ? (Woff + (size_t)o * 192) : (Wwt + (size_t)(o - 384) * 192);
    float s = 0.f;
#pragma unroll 4
    for (int k = 0; k < 192; k++) s = fmaf(A[k], Wq[k * 128 + c], s);
    Wcomb[(size_t)o * 128 + c] = s;
}

// y[o, n] = sum_c W[o,c] * x[c,n] with x-tile AND W-block staged in LDS.
// TILE_N=64 (lane = position), 4 waves split OG outputs (PT=OG/4 each).
// MODE 0: plain   MODE 1: tanh(.+bias)*0.35   MODE 2: .+bias
template<int C, int OG, int MODE>
__global__ __launch_bounds__(256)
void convT_kernel(const float* __restrict__ W, const float* __restrict__ bias,
                  const float* __restrict__ x, float* __restrict__ y)
{
    __shared__ float xs[C * 64];
    __shared__ float Wl[OG * C];
    int tid = threadIdx.x;
    int n0 = blockIdx.x * 64;
    int og0 = blockIdx.y * OG;
    for (int k = tid; k < C * 64; k += 256) xs[k] = x[(size_t)(k >> 6) * N_Q + n0 + (k & 63)];
    for (int k = tid; k < OG * C; k += 256) Wl[k] = W[(size_t)(og0 + k / C) * C + (k % C)];
    __syncthreads();

    int wv = tid >> 6, lane = tid & 63;
    constexpr int PT = OG / 4;
    float acc[PT];
#pragma unroll
    for (int i = 0; i < PT; i++) acc[i] = 0.f;
    for (int c = 0; c < C; c++) {
        float xv = xs[c * 64 + lane];           // 2-way bank aliasing: free
#pragma unroll
        for (int i = 0; i < PT; i++)
            acc[i] = fmaf(Wl[(wv * PT + i) * C + c], xv, acc[i]);   // LDS broadcast
    }
#pragma unroll
    for (int i = 0; i < PT; i++) {
        int o = og0 + wv * PT + i;
        float r = acc[i];
        if constexpr (MODE == 1) r = tanhf(r + bias[o]) * 0.35f;
        if constexpr (MODE == 2) r = r + bias[o];
        y[(size_t)o * N_Q + n0 + lane] = r;
    }
}

// softmax over the 16 (s,p) logit rows per head, in-place; thread per (h,n)
__global__ __launch_bounds__(256)
void softmax16_kernel(float* __restrict__ aw)
{
    int idx = blockIdx.x * 256 + threadIdx.x;   // 0..32767
    int h = idx >> 12;
    int n = idx & 4095;
    float v[16];
    float m = -1e30f;
#pragma unroll
    for (int i = 0; i < 16; i++) { v[i] = aw[(h * 16 + i) * N_Q + n]; m = fmaxf(m, v[i]); }
    float ssum = 0.f;
#pragma unroll
    for (int i = 0; i < 16; i++) { v[i] = __expf(v[i] - m); ssum += v[i]; }
    float inv = 1.0f / ssum;
#pragma unroll
    for (int i = 0; i < 16; i++) aw[(h * 16 + i) * N_Q + n] = v[i] * inv;
}

// [C, Nv] f32 -> [Nv, C] fp16 via LDS tile (coalesced both sides)
template<int C, int P>
__global__ __launch_bounds__(256)
void transpose_h_kernel(const float* __restrict__ src, __half* __restrict__ dst, int Nv)
{
    __shared__ float lds[P][C + 1];
    int tid = threadIdx.x;
    int pos0 = blockIdx.x * P;
    for (int k = tid; k < P * C; k += 256) {
        int c = k / P, p = k % P;
        lds[p][c] = src[c * Nv + pos0 + p];
    }
    __syncthreads();
    for (int k = tid; k < P * C; k += 256) {
        int p = k / C, c = k % C;
        dst[(pos0 + p) * C + c] = __float2half(lds[p][c]);
    }
}

// valT[pos][og0..og0+OG) fp16 = Wv(rows og0..og0+OG) @ v(C x Nv), 64-pos tile.
template<int C, int OG>
__global__ __launch_bounds__(256)
void valconv_kernel(const float* __restrict__ Wv, const float* __restrict__ v,
                    __half* __restrict__ valT, int Nv)
{
    __shared__ float Wl[OG][C];
    __shared__ __half outs[64 * OG];
    int tid = threadIdx.x;
    int p0 = blockIdx.x * 64;
    int og0 = blockIdx.y * OG;
    for (int k = tid; k < OG * C; k += 256) Wl[k / C][k % C] = Wv[(size_t)(og0 + k / C) * C + (k % C)];
    __syncthreads();

    int osub = tid >> 6;
    int lane = tid & 63;
    constexpr int PT = OG / 4;
    float acc[PT];
#pragma unroll
    for (int i = 0; i < PT; i++) acc[i] = 0.f;
    for (int c = 0; c < C; c++) {
        float vv = v[(size_t)c * Nv + p0 + lane];
#pragma unroll
        for (int i = 0; i < PT; i++)
            acc[i] = fmaf(Wl[osub * PT + i][c], vv, acc[i]);
    }
#pragma unroll
    for (int i = 0; i < PT; i++)
        outs[lane * OG + osub * PT + i] = __float2half(acc[i]);
    __syncthreads();

    unsigned int* dst = (unsigned int*)valT;
    const unsigned int* src = (const unsigned int*)outs;
    constexpr int UPP = OG / 2;
    for (int k = tid; k < 64 * UPP; k += 256) {
        int p = k / UPP, i = k % UPP;
        dst[(size_t)(p0 + p) * (HIDDEN / 2) + (og0 / 2) + i] = src[p * UPP + i];
    }
}

// main deformable sampling; blockIdx = (n-tile, head, s*4+p)
__global__ __launch_bounds__(256)
void sample_kernel(const float* __restrict__ offb, const float* __restrict__ awb,
                   const __half* __restrict__ v0T, const __half* __restrict__ val1T,
                   const __half* __restrict__ val2T, const __half* __restrict__ val3T,
                   const float* __restrict__ Wv0,
                   float* __restrict__ accb)
{
    int tid = threadIdx.x;
    int n = blockIdx.x * 256 + tid;
    int h = blockIdx.y;
    int sp = blockIdx.z;
    int s = sp >> 2, p = sp & 3;

    int wx = n & 15, hy = (n >> 4) & 15, dz = n >> 8;
    const float step = 2.0f / 15.0f;
    float bx = -1.f + wx * step;
    float by = -1.f + hy * step;
    float bz = -1.f + dz * step;

    float acc[HEAD_DIM];
#pragma unroll
    for (int j = 0; j < HEAD_DIM; j++) acc[j] = 0.f;

    int S = 64;
    const __half* srcT = v0T;
    if (s == 1)      { S = 32; srcT = val1T; }
    else if (s == 2) { S = 16; srcT = val2T; }
    else if (s == 3) { S = 8;  srcT = val3T; }
    float fS = (float)S;

    int orow = ((h * 4 + s) * 4 + p) * 3;
    float ox = offb[(orow + 0) * N_Q + n];
    float oy = offb[(orow + 1) * N_Q + n];
    float oz = offb[(orow + 2) * N_Q + n];
    float awv = awb[(h * 16 + s * 4 + p) * N_Q + n];

    float ix = fminf(fmaxf(((bx + ox + 1.f) * fS - 1.f) * 0.5f, 0.f), fS - 1.f);
    float iy = fminf(fmaxf(((by + oy + 1.f) * fS - 1.f) * 0.5f, 0.f), fS - 1.f);
    float iz = fminf(fmaxf(((bz + oz + 1.f) * fS - 1.f) * 0.5f, 0.f), fS - 1.f);

    float x0f = floorf(ix), y0f = floorf(iy), z0f = floorf(iz);
    float fx = ix - x0f, fy = iy - y0f, fz = iz - z0f;
    int x0 = (int)x0f, y0 = (int)y0f, z0 = (int)z0f;
    int x1 = min(x0 + 1, S - 1), y1 = min(y0 + 1, S - 1), z1 = min(z0 + 1, S - 1);

    int r000 = (z0 * S + y0) * S + x0, r001 = (z0 * S + y0) * S + x1;
    int r010 = (z0 * S + y1) * S + x0, r011 = (z0 * S + y1) * S + x1;
    int r100 = (z1 * S + y0) * S + x0, r101 = (z1 * S + y0) * S + x1;
    int r110 = (z1 * S + y1) * S + x0, r111 = (z1 * S + y1) * S + x1;

    float gx1 = fx, gx0 = 1.f - fx;
    float gy1 = fy, gy0 = 1.f - fy;
    float gz1 = fz, gz0 = 1.f - fz;
    float w000 = gz0 * gy0 * gx0 * awv, w001 = gz0 * gy0 * gx1 * awv;
    float w010 = gz0 * gy1 * gx0 * awv, w011 = gz0 * gy1 * gx1 * awv;
    float w100 = gz1 * gy0 * gx0 * awv, w101 = gz1 * gy0 * gx1 * awv;
    float w110 = gz1 * gy1 * gx0 * awv, w111 = gz1 * gy1 * gx1 * awv;

    if (s == 0) {
        const float* Wvh = Wv0 + h * HEAD_DIM * 32;
#pragma unroll
        for (int c8 = 0; c8 < 32; c8 += 8) {
            float u[8] = {0.f, 0.f, 0.f, 0.f, 0.f, 0.f, 0.f, 0.f};
            fma8h(u, w000, srcT + r000 * 32 + c8);
            fma8h(u, w001, srcT + r001 * 32 + c8);
            fma8h(u, w010, srcT + r010 * 32 + c8);
            fma8h(u, w011, srcT + r011 * 32 + c8);
            fma8h(u, w100, srcT + r100 * 32 + c8);
            fma8h(u, w101, srcT + r101 * 32 + c8);
            fma8h(u, w110, srcT + r110 * 32 + c8);
            fma8h(u, w111, srcT + r111 * 32 + c8);
#pragma unroll
            for (int j = 0; j < HEAD_DIM; j++) {
                const float* wp = Wvh + j * 32 + c8;
                float4 wa = ld4(wp), wb = ld4(wp + 4);
                acc[j] = fmaf(wa.x, u[0], fmaf(wa.y, u[1], fmaf(wa.z, u[2], fmaf(wa.w, u[3],
                         fmaf(wb.x, u[4], fmaf(wb.y, u[5], fmaf(wb.z, u[6], fmaf(wb.w, u[7], acc[j]))))))));
            }
        }
    } else {
        const __half* base = srcT + h * HEAD_DIM;
        corner24(acc, w000, base + (size_t)r000 * HIDDEN);
        corner24(acc, w001, base + (size_t)r001 * HIDDEN);
        corner24(acc, w010, base + (size_t)r010 * HIDDEN);
        corner24(acc, w011, base + (size_t)r011 * HIDDEN);
        corner24(acc, w100, base + (size_t)r100 * HIDDEN);
        corner24(acc, w101, base + (size_t)r101 * HIDDEN);
        corner24(acc, w110, base + (size_t)r110 * HIDDEN);
        corner24(acc, w111, base + (size_t)r111 * HIDDEN);
    }

    float* ab = accb + (size_t)sp * HIDDEN * N_Q;
#pragma unroll
    for (int j = 0; j < HEAD_DIM; j++) ab[(h * HEAD_DIM + j) * N_Q + n] = acc[j];
}

// accsum[i] = sum over the 16 (s,p) slices  (float4-vectorized)
__global__ __launch_bounds__(256)
void accsum_kernel(const float* __restrict__ accb, float* __restrict__ accsum)
{
    int i = blockIdx.x * 256 + threadIdx.x;
    const int SB4 = HIDDEN * N_Q / 4;
    const float4* src = (const float4*)accb;
    float4 a = src[i];
#pragma unroll
    for (int sp = 1; sp < 16; sp++) {
        float4 b = src[sp * SB4 + i];
        a.x += b.x; a.y += b.y; a.z += b.z; a.w += b.w;
    }
    ((float4*)accsum)[i] = a;
}

// InstanceNorm3d per channel (in-place on d_out)
__global__ __launch_bounds__(256)
void inorm_kernel(float* __restrict__ out, const float* __restrict__ gamma,
                  const float* __restrict__ beta)
{
    int o = blockIdx.x;
    int tid = threadIdx.x;
    float s = 0.f, s2 = 0.f;
    for (int n = tid; n < N_Q; n += 256) {
        float v = out[o * N_Q + n];
        s += v; s2 += v * v;
    }
    __shared__ float rs[256], rs2[256];
    rs[tid] = s; rs2[tid] = s2;
    __syncthreads();
    for (int k = 128; k > 0; k >>= 1) {
        if (tid < k) { rs[tid] += rs[tid + k]; rs2[tid] += rs2[tid + k]; }
        __syncthreads();
    }
    float mu = rs[0] * (1.0f / N_Q);
    float var = rs2[0] * (1.0f / N_Q) - mu * mu;
    float rstd = rsqrtf(var + 1e-5f);
    float g = gamma[o] * rstd;
    float b = beta[o] - mu * g;
    for (int n = tid; n < N_Q; n += 256) {
        out[o * N_Q + n] = fmaf(out[o * N_Q + n], g, b);
    }
}

extern "C" void kernel_launch(void* const* d_in, const int* in_sizes, int n_in,
                              void* d_out, int out_size, void* d_ws, size_t ws_size,
                              hipStream_t stream)
{
    const float* qf    = (const float*)d_in[0];
    const float* v0    = (const float*)d_in[1];
    const float* v1    = (const float*)d_in[2];
    const float* v2    = (const float*)d_in[3];
    const float* v3    = (const float*)d_in[4];
    const float* Wq    = (const float*)d_in[5];
    const float* Wv0   = (const float*)d_in[6];
    const float* Wv1   = (const float*)d_in[7];
    const float* Wv2   = (const float*)d_in[8];
    const float* Wv3   = (const float*)d_in[9];
    const float* Woff  = (const float*)d_in[10];
    const float* boff  = (const float*)d_in[11];
    const float* Wwt   = (const float*)d_in[12];
    const float* bwt   = (const float*)d_in[13];
    const float* Wout  = (const float*)d_in[14];
    const float* gamma = (const float*)d_in[15];
    const float* beta  = (const float*)d_in[16];
    float* out = (float*)d_out;

    float* ws     = (float*)d_ws;
    float*  Wcomb  = ws;                        // 512*128      = 65536 f
    float*  offb   = Wcomb  + 65536;            // 384*4096     = 1572864 f
    float*  awb    = offb   + 1572864;          // 128*4096     = 524288 f
    __half* v0T    = (__half*)(awb + 524288);   // 262144*32 h  (4194304 f)
    __half* val1T  = (__half*)((float*)v0T + 4194304);   // 32768*192 h (3145728 f)
    __half* val2T  = (__half*)((float*)val1T + 3145728); // 4096*192 h (393216 f)
    __half* val3T  = (__half*)((float*)val2T + 393216);  // 512*192 h (49152 f)
    float*  accb   = (float*)val3T + 49152;     // 16*786432 f
    float*  accsum = accb   + 12582912;         // 786432 f

    // fold Wq into the offset/weight projections: Wcomb = [Woff;Wwt] @ Wq
    wcomb_kernel<<<256, 256, 0, stream>>>(Woff, Wwt, Wq, Wcomb);
    // offsets = tanh(WoffQ @ qf + boff) * 0.35
    convT_kernel<128, 32, 1><<<dim3(64, 12), 256, 0, stream>>>(Wcomb, boff, qf, offb);
    // attention logits (+bias), softmax over 16 per head (in-place)
    convT_kernel<128, 32, 2><<<dim3(64, 4), 256, 0, stream>>>(Wcomb + 384 * 128, bwt, qf, awb);
    softmax16_kernel<<<128, 256, 0, stream>>>(awb);
    // v0 -> spatial-major fp16 (raw channels; conv fused into sampling)
    transpose_h_kernel<32, 256><<<1024, 256, 0, stream>>>(v0, v0T, 262144);
    // precomputed value convs (fp16, pos-major) for s=1,2,3
    valconv_kernel<64, 24><<<dim3(512, 8), 256, 0, stream>>>(Wv1, v1, val1T, 32768);
    valconv_kernel<128, 12><<<dim3(64, 16), 256, 0, stream>>>(Wv2, v2, val2T, 4096);
    valconv_kernel<256, 8><<<dim3(8, 24), 256, 0, stream>>>(Wv3, v3, val3T, 512);
    // deformable sampling — one (scale,point) per block
    sample_kernel<<<dim3(16, 8, 16), 256, 0, stream>>>(offb, awb, v0T, val1T, val2T, val3T,
                                                       Wv0, accb);
    // reduce the 16 (s,p) slices
    accsum_kernel<<<768, 256, 0, stream>>>(accb, accsum);
    // final 1x1 conv
    convT_kernel<192, 32, 0><<<dim3(64, 4), 256, 0, stream>>>(Wout, nullptr, accsum, out);
    // instance norm in-place
    inorm_kernel<<<128, 256, 0, stream>>>(out, gamma, beta);
}

// Round 9
// 281.754 us; speedup vs baseline: 2.7874x; 1.1101x over previous
//
#include <hip/hip_runtime.h>
#include <hip/hip_fp16.h>
#include <cmath>

#define N_Q 4096
#define HEADS 8
#define HEAD_DIM 24
#define HIDDEN 192

__device__ __forceinline__ float4 ld4(const float* p) { return *(const float4*)p; }

// accumulate u[0..7] += w * fp16x8 at p (16B aligned)
__device__ __forceinline__ void fma8h(float* u, float w, const __half* p) {
    uint4 raw = *(const uint4*)p;
    const __half2* h2 = reinterpret_cast<const __half2*>(&raw);
#pragma unroll
    for (int k = 0; k < 4; k++) {
        float2 f = __half22float2(h2[k]);
        u[2 * k]     = fmaf(w, f.x, u[2 * k]);
        u[2 * k + 1] = fmaf(w, f.y, u[2 * k + 1]);
    }
}

// acc[0..23] += w * fp16x24 at p (p 16B aligned: head offsets are 48B multiples)
__device__ __forceinline__ void corner24(float* acc, float w, const __half* p) {
    fma8h(acc,      w, p);
    fma8h(acc + 8,  w, p + 8);
    fma8h(acc + 16, w, p + 16);
}

// Wcomb[o][c] (512x128) = concat(Woff,Wwt)[o][k] @ Wq[k][c]  (K=192)
// also builds biasc[512] = concat(boff, bwt)
__global__ __launch_bounds__(256)
void wcomb_kernel(const float* __restrict__ Woff, const float* __restrict__ Wwt,
                  const float* __restrict__ Wq, const float* __restrict__ boff,
                  const float* __restrict__ bwt, float* __restrict__ Wcomb,
                  float* __restrict__ biasc)
{
    int o = blockIdx.x * 2 + (threadIdx.x >> 7);
    int c = threadIdx.x & 127;
    const float* A = (o < 384) ? (Woff + (size_t)o * 192) : (Wwt + (size_t)(o - 384) * 192);
    float s = 0.f;
#pragma unroll 4
    for (int k = 0; k < 192; k++) s = fmaf(A[k], Wq[k * 128 + c], s);
    Wcomb[(size_t)o * 128 + c] = s;
    if (c == 0) biasc[o] = (o < 384) ? boff[o] : bwt[o - 384];
}

// y[o, n] = sum_c W[o,c] * x[c,n] with x-tile AND W-block staged in LDS.
// TILE_N=64 (lane = position), 4 waves split OG outputs (PT=OG/4 each).
// MODE 0: plain   MODE 3: o<384 ? tanh(.+bias)*0.35 : .+bias
template<int C, int OG, int MODE>
__global__ __launch_bounds__(256)
void convT_kernel(const float* __restrict__ W, const float* __restrict__ bias,
                  const float* __restrict__ x, float* __restrict__ y)
{
    __shared__ float xs[C * 64];
    __shared__ float Wl[OG * C];
    int tid = threadIdx.x;
    int n0 = blockIdx.x * 64;
    int og0 = blockIdx.y * OG;
    for (int k = tid; k < C * 64; k += 256) xs[k] = x[(size_t)(k >> 6) * N_Q + n0 + (k & 63)];
    for (int k = tid; k < OG * C; k += 256) Wl[k] = W[(size_t)(og0 + k / C) * C + (k % C)];
    __syncthreads();

    int wv = tid >> 6, lane = tid & 63;
    constexpr int PT = OG / 4;
    float acc[PT];
#pragma unroll
    for (int i = 0; i < PT; i++) acc[i] = 0.f;
    for (int c = 0; c < C; c++) {
        float xv = xs[c * 64 + lane];           // 2-way bank aliasing: free
#pragma unroll
        for (int i = 0; i < PT; i++)
            acc[i] = fmaf(Wl[(wv * PT + i) * C + c], xv, acc[i]);   // LDS broadcast
    }
#pragma unroll
    for (int i = 0; i < PT; i++) {
        int o = og0 + wv * PT + i;
        float r = acc[i];
        if constexpr (MODE == 3) {
            r = (o < 384) ? tanhf(r + bias[o]) * 0.35f : r + bias[o];
        }
        y[(size_t)o * N_Q + n0 + lane] = r;
    }
}

// softmax over the 16 (s,p) logit rows per head, in-place; thread per (h,n)
__global__ __launch_bounds__(256)
void softmax16_kernel(float* __restrict__ aw)
{
    int idx = blockIdx.x * 256 + threadIdx.x;   // 0..32767
    int h = idx >> 12;
    int n = idx & 4095;
    float v[16];
    float m = -1e30f;
#pragma unroll
    for (int i = 0; i < 16; i++) { v[i] = aw[(h * 16 + i) * N_Q + n]; m = fmaxf(m, v[i]); }
    float ssum = 0.f;
#pragma unroll
    for (int i = 0; i < 16; i++) { v[i] = __expf(v[i] - m); ssum += v[i]; }
    float inv = 1.0f / ssum;
#pragma unroll
    for (int i = 0; i < 16; i++) aw[(h * 16 + i) * N_Q + n] = v[i] * inv;
}

// [C, Nv] f32 -> [Nv, C] fp16 via LDS tile (coalesced both sides)
template<int C, int P>
__global__ __launch_bounds__(256)
void transpose_h_kernel(const float* __restrict__ src, __half* __restrict__ dst, int Nv)
{
    __shared__ float lds[P][C + 1];
    int tid = threadIdx.x;
    int pos0 = blockIdx.x * P;
    for (int k = tid; k < P * C; k += 256) {
        int c = k / P, p = k % P;
        lds[p][c] = src[c * Nv + pos0 + p];
    }
    __syncthreads();
    for (int k = tid; k < P * C; k += 256) {
        int p = k / C, c = k % C;
        dst[(pos0 + p) * C + c] = __float2half(lds[p][c]);
    }
}

// valT[pos][og0..og0+OG) fp16 = Wv(rows og0..og0+OG) @ v(C x Nv), 64-pos tile.
template<int C, int OG>
__device__ __forceinline__ void valconv_body(const float* __restrict__ Wv,
                                             const float* __restrict__ v,
                                             __half* __restrict__ valT, int Nv,
                                             int bx, int by, int tid)
{
    __shared__ float Wl[OG][C];
    __shared__ __half outs[64 * OG];
    int p0 = bx * 64;
    int og0 = by * OG;
    for (int k = tid; k < OG * C; k += 256) Wl[k / C][k % C] = Wv[(size_t)(og0 + k / C) * C + (k % C)];
    __syncthreads();

    int osub = tid >> 6;
    int lane = tid & 63;
    constexpr int PT = OG / 4;
    float acc[PT];
#pragma unroll
    for (int i = 0; i < PT; i++) acc[i] = 0.f;
    for (int c = 0; c < C; c++) {
        float vv = v[(size_t)c * Nv + p0 + lane];
#pragma unroll
        for (int i = 0; i < PT; i++)
            acc[i] = fmaf(Wl[osub * PT + i][c], vv, acc[i]);
    }
#pragma unroll
    for (int i = 0; i < PT; i++)
        outs[lane * OG + osub * PT + i] = __float2half(acc[i]);
    __syncthreads();

    unsigned int* dst = (unsigned int*)valT;
    const unsigned int* src = (const unsigned int*)outs;
    constexpr int UPP = OG / 2;
    for (int k = tid; k < 64 * UPP; k += 256) {
        int p = k / UPP, i = k % UPP;
        dst[(size_t)(p0 + p) * (HIDDEN / 2) + (og0 / 2) + i] = src[p * UPP + i];
    }
}

// all three value convs in one launch (concurrent instead of serial)
__global__ __launch_bounds__(256)
void valconv_all_kernel(const float* __restrict__ Wv1, const float* __restrict__ v1,
                        __half* __restrict__ val1T,
                        const float* __restrict__ Wv2, const float* __restrict__ v2,
                        __half* __restrict__ val2T,
                        const float* __restrict__ Wv3, const float* __restrict__ v3,
                        __half* __restrict__ val3T)
{
    int id = blockIdx.x;
    int tid = threadIdx.x;
    if (id < 4096) {                     // scale 1: 512 tiles x 8 og-blocks
        valconv_body<64, 24>(Wv1, v1, val1T, 32768, id & 511, id >> 9, tid);
    } else if (id < 5120) {              // scale 2: 64 tiles x 16 og-blocks
        int i2 = id - 4096;
        valconv_body<128, 12>(Wv2, v2, val2T, 4096, i2 & 63, i2 >> 6, tid);
    } else {                             // scale 3: 8 tiles x 24 og-blocks
        int i3 = id - 5120;
        valconv_body<256, 8>(Wv3, v3, val3T, 512, i3 & 7, i3 >> 3, tid);
    }
}

// main deformable sampling; 1D grid, id = sp*128 + h*16 + t.
// Consecutive ids vary t fastest -> all 128 blocks of slice t land on XCD t%8
// (round-robin dispatch), so one L2 copy of the slab serves them.
__global__ __launch_bounds__(256)
void sample_kernel(const float* __restrict__ offb, const float* __restrict__ awb,
                   const __half* __restrict__ v0T, const __half* __restrict__ val1T,
                   const __half* __restrict__ val2T, const __half* __restrict__ val3T,
                   const float* __restrict__ Wv0,
                   __half* __restrict__ accb)
{
    int tid = threadIdx.x;
    int id = blockIdx.x;
    int t = id & 15;
    int h = (id >> 4) & 7;
    int sp = id >> 7;
    int n = t * 256 + tid;
    int s = sp >> 2, p = sp & 3;

    int wx = n & 15, hy = (n >> 4) & 15, dz = n >> 8;
    const float step = 2.0f / 15.0f;
    float bx = -1.f + wx * step;
    float by = -1.f + hy * step;
    float bz = -1.f + dz * step;

    float acc[HEAD_DIM];
#pragma unroll
    for (int j = 0; j < HEAD_DIM; j++) acc[j] = 0.f;

    int S = 64;
    const __half* srcT = v0T;
    if (s == 1)      { S = 32; srcT = val1T; }
    else if (s == 2) { S = 16; srcT = val2T; }
    else if (s == 3) { S = 8;  srcT = val3T; }
    float fS = (float)S;

    int orow = ((h * 4 + s) * 4 + p) * 3;
    float ox = offb[(orow + 0) * N_Q + n];
    float oy = offb[(orow + 1) * N_Q + n];
    float oz = offb[(orow + 2) * N_Q + n];
    float awv = awb[(h * 16 + s * 4 + p) * N_Q + n];

    float ix = fminf(fmaxf(((bx + ox + 1.f) * fS - 1.f) * 0.5f, 0.f), fS - 1.f);
    float iy = fminf(fmaxf(((by + oy + 1.f) * fS - 1.f) * 0.5f, 0.f), fS - 1.f);
    float iz = fminf(fmaxf(((bz + oz + 1.f) * fS - 1.f) * 0.5f, 0.f), fS - 1.f);

    float x0f = floorf(ix), y0f = floorf(iy), z0f = floorf(iz);
    float fx = ix - x0f, fy = iy - y0f, fz = iz - z0f;
    int x0 = (int)x0f, y0 = (int)y0f, z0 = (int)z0f;
    int x1 = min(x0 + 1, S - 1), y1 = min(y0 + 1, S - 1), z1 = min(z0 + 1, S - 1);

    int r000 = (z0 * S + y0) * S + x0, r001 = (z0 * S + y0) * S + x1;
    int r010 = (z0 * S + y1) * S + x0, r011 = (z0 * S + y1) * S + x1;
    int r100 = (z1 * S + y0) * S + x0, r101 = (z1 * S + y0) * S + x1;
    int r110 = (z1 * S + y1) * S + x0, r111 = (z1 * S + y1) * S + x1;

    float gx1 = fx, gx0 = 1.f - fx;
    float gy1 = fy, gy0 = 1.f - fy;
    float gz1 = fz, gz0 = 1.f - fz;
    float w000 = gz0 * gy0 * gx0 * awv, w001 = gz0 * gy0 * gx1 * awv;
    float w010 = gz0 * gy1 * gx0 * awv, w011 = gz0 * gy1 * gx1 * awv;
    float w100 = gz1 * gy0 * gx0 * awv, w101 = gz1 * gy0 * gx1 * awv;
    float w110 = gz1 * gy1 * gx0 * awv, w111 = gz1 * gy1 * gx1 * awv;

    if (s == 0) {
        const float* Wvh = Wv0 + h * HEAD_DIM * 32;
#pragma unroll
        for (int c8 = 0; c8 < 32; c8 += 8) {
            float u[8] = {0.f, 0.f, 0.f, 0.f, 0.f, 0.f, 0.f, 0.f};
            fma8h(u, w000, srcT + r000 * 32 + c8);
            fma8h(u, w001, srcT + r001 * 32 + c8);
            fma8h(u, w010, srcT + r010 * 32 + c8);
            fma8h(u, w011, srcT + r011 * 32 + c8);
            fma8h(u, w100, srcT + r100 * 32 + c8);
            fma8h(u, w101, srcT + r101 * 32 + c8);
            fma8h(u, w110, srcT + r110 * 32 + c8);
            fma8h(u, w111, srcT + r111 * 32 + c8);
#pragma unroll
            for (int j = 0; j < HEAD_DIM; j++) {
                const float* wp = Wvh + j * 32 + c8;
                float4 wa = ld4(wp), wb = ld4(wp + 4);
                acc[j] = fmaf(wa.x, u[0], fmaf(wa.y, u[1], fmaf(wa.z, u[2], fmaf(wa.w, u[3],
                         fmaf(wb.x, u[4], fmaf(wb.y, u[5], fmaf(wb.z, u[6], fmaf(wb.w, u[7], acc[j]))))))));
            }
        }
    } else {
        const __half* base = srcT + h * HEAD_DIM;
        corner24(acc, w000, base + (size_t)r000 * HIDDEN);
        corner24(acc, w001, base + (size_t)r001 * HIDDEN);
        corner24(acc, w010, base + (size_t)r010 * HIDDEN);
        corner24(acc, w011, base + (size_t)r011 * HIDDEN);
        corner24(acc, w100, base + (size_t)r100 * HIDDEN);
        corner24(acc, w101, base + (size_t)r101 * HIDDEN);
        corner24(acc, w110, base + (size_t)r110 * HIDDEN);
        corner24(acc, w111, base + (size_t)r111 * HIDDEN);
    }

    __half* ab = accb + (size_t)sp * HIDDEN * N_Q;
#pragma unroll
    for (int j = 0; j < HEAD_DIM; j++) ab[(h * HEAD_DIM + j) * N_Q + n] = __float2half(acc[j]);
}

// accsum[i] = sum over the 16 (s,p) fp16 slices  (uint4 = 8 halfs per thread)
__global__ __launch_bounds__(256)
void accsum_kernel(const __half* __restrict__ accb, float* __restrict__ accsum)
{
    int i = blockIdx.x * 256 + threadIdx.x;       // 0 .. 98303
    const int SB8 = HIDDEN * N_Q / 8;
    const uint4* src = (const uint4*)accb;
    float a[8] = {0.f, 0.f, 0.f, 0.f, 0.f, 0.f, 0.f, 0.f};
#pragma unroll
    for (int sp = 0; sp < 16; sp++) {
        uint4 r = src[sp * SB8 + i];
        const __half2* h2 = (const __half2*)&r;
#pragma unroll
        for (int k = 0; k < 4; k++) {
            float2 f = __half22float2(h2[k]);
            a[2 * k] += f.x; a[2 * k + 1] += f.y;
        }
    }
    float4* dst = (float4*)accsum;
    dst[i * 2]     = make_float4(a[0], a[1], a[2], a[3]);
    dst[i * 2 + 1] = make_float4(a[4], a[5], a[6], a[7]);
}

// InstanceNorm3d per channel (in-place on d_out)
__global__ __launch_bounds__(256)
void inorm_kernel(float* __restrict__ out, const float* __restrict__ gamma,
                  const float* __restrict__ beta)
{
    int o = blockIdx.x;
    int tid = threadIdx.x;
    float s = 0.f, s2 = 0.f;
    for (int n = tid; n < N_Q; n += 256) {
        float v = out[o * N_Q + n];
        s += v; s2 += v * v;
    }
    __shared__ float rs[256], rs2[256];
    rs[tid] = s; rs2[tid] = s2;
    __syncthreads();
    for (int k = 128; k > 0; k >>= 1) {
        if (tid < k) { rs[tid] += rs[tid + k]; rs2[tid] += rs2[tid + k]; }
        __syncthreads();
    }
    float mu = rs[0] * (1.0f / N_Q);
    float var = rs2[0] * (1.0f / N_Q) - mu * mu;
    float rstd = rsqrtf(var + 1e-5f);
    float g = gamma[o] * rstd;
    float b = beta[o] - mu * g;
    for (int n = tid; n < N_Q; n += 256) {
        out[o * N_Q + n] = fmaf(out[o * N_Q + n], g, b);
    }
}

extern "C" void kernel_launch(void* const* d_in, const int* in_sizes, int n_in,
                              void* d_out, int out_size, void* d_ws, size_t ws_size,
                              hipStream_t stream)
{
    const float* qf    = (const float*)d_in[0];
    const float* v0    = (const float*)d_in[1];
    const float* v1    = (const float*)d_in[2];
    const float* v2    = (const float*)d_in[3];
    const float* v3    = (const float*)d_in[4];
    const float* Wq    = (const float*)d_in[5];
    const float* Wv0   = (const float*)d_in[6];
    const float* Wv1   = (const float*)d_in[7];
    const float* Wv2   = (const float*)d_in[8];
    const float* Wv3   = (const float*)d_in[9];
    const float* Woff  = (const float*)d_in[10];
    const float* boff  = (const float*)d_in[11];
    const float* Wwt   = (const float*)d_in[12];
    const float* bwt   = (const float*)d_in[13];
    const float* Wout  = (const float*)d_in[14];
    const float* gamma = (const float*)d_in[15];
    const float* beta  = (const float*)d_in[16];
    float* out = (float*)d_out;

    float* ws     = (float*)d_ws;
    float*  Wcomb  = ws;                                 // 512*128 = 65536 f
    float*  biasc  = Wcomb  + 65536;                     // 512 f
    float*  offb   = biasc  + 512;                       // 384*4096 = 1572864 f
    float*  awb    = offb   + 1572864;                   // 128*4096 = 524288 f  (contiguous after offb!)
    __half* v0T    = (__half*)(awb + 524288);            // 262144*32 h (4194304 f)
    __half* val1T  = (__half*)((float*)v0T + 4194304);   // 32768*192 h (3145728 f)
    __half* val2T  = (__half*)((float*)val1T + 3145728); // 4096*192 h (393216 f)
    __half* val3T  = (__half*)((float*)val2T + 393216);  // 512*192 h (49152 f)
    __half* accb   = (__half*)((float*)val3T + 49152);   // 16*192*4096 h (6291456 f)
    float*  accsum = (float*)accb + 6291456;             // 786432 f

    // fold Wq into the offset/weight projections + combined bias
    wcomb_kernel<<<256, 256, 0, stream>>>(Woff, Wwt, Wq, boff, bwt, Wcomb, biasc);
    // offsets (tanh) + attention logits (+bias) in ONE pass over qf
    convT_kernel<128, 32, 3><<<dim3(64, 16), 256, 0, stream>>>(Wcomb, biasc, qf, offb);
    // softmax over 16 per head (in-place on awb rows)
    softmax16_kernel<<<128, 256, 0, stream>>>(awb);
    // v0 -> spatial-major fp16 (raw channels; conv fused into sampling)
    transpose_h_kernel<32, 256><<<1024, 256, 0, stream>>>(v0, v0T, 262144);
    // all precomputed value convs in one launch
    valconv_all_kernel<<<5312, 256, 0, stream>>>(Wv1, v1, val1T, Wv2, v2, val2T, Wv3, v3, val3T);
    // deformable sampling — XCD-locality swizzled 1D grid
    sample_kernel<<<2048, 256, 0, stream>>>(offb, awb, v0T, val1T, val2T, val3T, Wv0, accb);
    // reduce the 16 (s,p) fp16 slices
    accsum_kernel<<<384, 256, 0, stream>>>(accb, accsum);
    // final 1x1 conv
    convT_kernel<192, 32, 0><<<dim3(64, 4), 256, 0, stream>>>(Wout, nullptr, accsum, out);
    // instance norm in-place
    inorm_kernel<<<128, 256, 0, stream>>>(out, gamma, beta);
}

// Round 10
// 257.317 us; speedup vs baseline: 3.0521x; 1.0950x over previous
//
#include <hip/hip_runtime.h>
#include <hip/hip_fp16.h>
#include <cmath>

#define N_Q 4096
#define HEADS 8
#define HEAD_DIM 24
#define HIDDEN 192

__device__ __forceinline__ float4 ld4(const float* p) { return *(const float4*)p; }

// accumulate u[0..7] += w * fp16x8 at p (16B aligned)
__device__ __forceinline__ void fma8h(float* u, float w, const __half* p) {
    uint4 raw = *(const uint4*)p;
    const __half2* h2 = reinterpret_cast<const __half2*>(&raw);
#pragma unroll
    for (int k = 0; k < 4; k++) {
        float2 f = __half22float2(h2[k]);
        u[2 * k]     = fmaf(w, f.x, u[2 * k]);
        u[2 * k + 1] = fmaf(w, f.y, u[2 * k + 1]);
    }
}

// acc[0..23] += w * fp16x24 at p
__device__ __forceinline__ void corner24(float* acc, float w, const __half* p) {
    fma8h(acc,      w, p);
    fma8h(acc + 8,  w, p + 8);
    fma8h(acc + 16, w, p + 16);
}

// ---------------- prep bodies (share one smem buffer) ----------------

// [32, 262144] f32 -> [262144, 32] fp16, 256-pos tile; smem >= 256*33*4 B
__device__ __forceinline__ void transpose_body(char* smem, const float* __restrict__ src,
                                               __half* __restrict__ dst, int bx, int tid)
{
    float (*lds)[33] = (float(*)[33])smem;
    const int Nv = 262144;
    int pos0 = bx * 256;
    for (int k = tid; k < 256 * 32; k += 256) {
        int c = k >> 8, p = k & 255;
        lds[p][c] = src[(size_t)c * Nv + pos0 + p];
    }
    __syncthreads();
    for (int k = tid; k < 256 * 32; k += 256) {
        int p = k >> 5, c = k & 31;
        dst[(size_t)(pos0 + p) * 32 + c] = __float2half(lds[p][c]);
    }
}

// valT[pos][og0..og0+OG) fp16 = Wv rows @ v(C x Nv), 64-pos tile
template<int C, int OG>
__device__ __forceinline__ void valconv_body(char* smem, const float* __restrict__ Wv,
                                             const float* __restrict__ v,
                                             __half* __restrict__ valT, int Nv,
                                             int bx, int by, int tid)
{
    float* Wl = (float*)smem;                       // OG*C floats
    __half* outs = (__half*)(smem + OG * C * 4);    // 64*OG halfs
    int p0 = bx * 64;
    int og0 = by * OG;
    for (int k = tid; k < OG * C; k += 256) Wl[k] = Wv[(size_t)(og0 + k / C) * C + (k % C)];
    __syncthreads();

    int osub = tid >> 6;
    int lane = tid & 63;
    constexpr int PT = OG / 4;
    float acc[PT];
#pragma unroll
    for (int i = 0; i < PT; i++) acc[i] = 0.f;
    for (int c = 0; c < C; c++) {
        float vv = v[(size_t)c * Nv + p0 + lane];
#pragma unroll
        for (int i = 0; i < PT; i++)
            acc[i] = fmaf(Wl[(osub * PT + i) * C + c], vv, acc[i]);
    }
#pragma unroll
    for (int i = 0; i < PT; i++)
        outs[lane * OG + osub * PT + i] = __float2half(acc[i]);
    __syncthreads();

    unsigned int* dst = (unsigned int*)valT;
    const unsigned int* src = (const unsigned int*)outs;
    constexpr int UPP = OG / 2;
    for (int k = tid; k < 64 * UPP; k += 256) {
        int p = k / UPP, i = k % UPP;
        dst[(size_t)(p0 + p) * (HIDDEN / 2) + (og0 / 2) + i] = src[p * UPP + i];
    }
}

// Wcomb[o][c] (512x128) = concat(Woff,Wwt)[o][:] @ Wq[:][c]; biasc = concat(boff,bwt)
__device__ __forceinline__ void wcomb_body(int bx, int tid,
                                           const float* __restrict__ Woff,
                                           const float* __restrict__ Wwt,
                                           const float* __restrict__ Wq,
                                           const float* __restrict__ boff,
                                           const float* __restrict__ bwt,
                                           float* __restrict__ Wcomb,
                                           float* __restrict__ biasc)
{
    int o = bx * 2 + (tid >> 7);
    int c = tid & 127;
    const float* A = (o < 384) ? (Woff + (size_t)o * 192) : (Wwt + (size_t)(o - 384) * 192);
    float s = 0.f;
#pragma unroll 4
    for (int k = 0; k < 192; k++) s = fmaf(A[k], Wq[k * 128 + c], s);
    Wcomb[(size_t)o * 128 + c] = s;
    if (c == 0) biasc[o] = (o < 384) ? boff[o] : bwt[o - 384];
}

// one launch for ALL independent prep work:
// ids [0,1024): v0 transpose; [1024,5120): valconv s1; [5120,6144): s2;
// [6144,6336): s3; [6336,6592): wcomb
__global__ __launch_bounds__(256)
void prep_kernel(const float* __restrict__ v0, __half* __restrict__ v0T,
                 const float* __restrict__ Wv1, const float* __restrict__ v1, __half* __restrict__ val1T,
                 const float* __restrict__ Wv2, const float* __restrict__ v2, __half* __restrict__ val2T,
                 const float* __restrict__ Wv3, const float* __restrict__ v3, __half* __restrict__ val3T,
                 const float* __restrict__ Woff, const float* __restrict__ Wwt,
                 const float* __restrict__ Wq, const float* __restrict__ boff,
                 const float* __restrict__ bwt, float* __restrict__ Wcomb,
                 float* __restrict__ biasc)
{
    __shared__ __align__(16) char smem[33792];
    int id = blockIdx.x;
    int tid = threadIdx.x;
    if (id < 1024) {
        transpose_body(smem, v0, v0T, id, tid);
    } else if (id < 5120) {
        int i1 = id - 1024;
        valconv_body<64, 24>(smem, Wv1, v1, val1T, 32768, i1 & 511, i1 >> 9, tid);
    } else if (id < 6144) {
        int i2 = id - 5120;
        valconv_body<128, 12>(smem, Wv2, v2, val2T, 4096, i2 & 63, i2 >> 6, tid);
    } else if (id < 6336) {
        int i3 = id - 6144;
        valconv_body<256, 8>(smem, Wv3, v3, val3T, 512, i3 & 7, i3 >> 3, tid);
    } else {
        wcomb_body(id - 6336, tid, Woff, Wwt, Wq, boff, bwt, Wcomb, biasc);
    }
}

// offsets + attention weights in one kernel. ob = 512-row output region:
// rows 0..383 = tanh offsets; rows 384..511 = softmaxed attention weights.
// blockIdx.y < 12 -> offset rows (tanh); >= 12 -> 2 heads' logits + in-block softmax.
__global__ __launch_bounds__(256)
void offaw_kernel(const float* __restrict__ Wcomb, const float* __restrict__ biasc,
                  const float* __restrict__ qf, float* __restrict__ ob)
{
    __shared__ float xs[128 * 64];   // 32KB
    __shared__ float Wl[32 * 128];   // 16KB
    __shared__ float ls[32 * 64];    // 8KB (logit exchange)
    int tid = threadIdx.x;
    int n0 = blockIdx.x * 64;
    int og0 = blockIdx.y * 32;
    for (int k = tid; k < 128 * 64; k += 256) xs[k] = qf[(size_t)(k >> 6) * N_Q + n0 + (k & 63)];
    for (int k = tid; k < 32 * 128; k += 256) Wl[k] = Wcomb[(size_t)og0 * 128 + k];
    __syncthreads();

    int wv = tid >> 6, lane = tid & 63;
    float acc[8];
#pragma unroll
    for (int i = 0; i < 8; i++) acc[i] = 0.f;
    for (int c = 0; c < 128; c++) {
        float xv = xs[c * 64 + lane];
#pragma unroll
        for (int i = 0; i < 8; i++)
            acc[i] = fmaf(Wl[(wv * 8 + i) * 128 + c], xv, acc[i]);
    }

    if (og0 < 384) {
#pragma unroll
        for (int i = 0; i < 8; i++) {
            int o = og0 + wv * 8 + i;
            ob[(size_t)o * N_Q + n0 + lane] = tanhf(acc[i] + biasc[o]) * 0.35f;
        }
    } else {
        // stage logits (+bias) to LDS, then softmax over each head's 16 rows
#pragma unroll
        for (int i = 0; i < 8; i++) {
            int o = og0 + wv * 8 + i;
            ls[(wv * 8 + i) * 64 + lane] = acc[i] + biasc[o];
        }
        __syncthreads();
        if (tid < 128) {
            int hl = tid >> 6;            // which of the block's 2 heads
            int n2 = tid & 63;
            float v[16];
            float m = -1e30f;
#pragma unroll
            for (int j = 0; j < 16; j++) { v[j] = ls[(hl * 16 + j) * 64 + n2]; m = fmaxf(m, v[j]); }
            float ssum = 0.f;
#pragma unroll
            for (int j = 0; j < 16; j++) { v[j] = __expf(v[j] - m); ssum += v[j]; }
            float inv = 1.0f / ssum;
            int orow = og0 + hl * 16;     // global row in [384,512)
#pragma unroll
            for (int j = 0; j < 16; j++)
                ob[(size_t)(orow + j) * N_Q + n0 + n2] = v[j] * inv;
        }
    }
}

// main deformable sampling; 1D grid, id = sp*128 + h*16 + t
__global__ __launch_bounds__(256)
void sample_kernel(const float* __restrict__ offb, const float* __restrict__ awb,
                   const __half* __restrict__ v0T, const __half* __restrict__ val1T,
                   const __half* __restrict__ val2T, const __half* __restrict__ val3T,
                   const float* __restrict__ Wv0,
                   __half* __restrict__ accb)
{
    int tid = threadIdx.x;
    int id = blockIdx.x;
    int t = id & 15;
    int h = (id >> 4) & 7;
    int sp = id >> 7;
    int n = t * 256 + tid;
    int s = sp >> 2, p = sp & 3;

    int wx = n & 15, hy = (n >> 4) & 15, dz = n >> 8;
    const float step = 2.0f / 15.0f;
    float bx = -1.f + wx * step;
    float by = -1.f + hy * step;
    float bz = -1.f + dz * step;

    float acc[HEAD_DIM];
#pragma unroll
    for (int j = 0; j < HEAD_DIM; j++) acc[j] = 0.f;

    int S = 64;
    const __half* srcT = v0T;
    if (s == 1)      { S = 32; srcT = val1T; }
    else if (s == 2) { S = 16; srcT = val2T; }
    else if (s == 3) { S = 8;  srcT = val3T; }
    float fS = (float)S;

    int orow = ((h * 4 + s) * 4 + p) * 3;
    float ox = offb[(orow + 0) * N_Q + n];
    float oy = offb[(orow + 1) * N_Q + n];
    float oz = offb[(orow + 2) * N_Q + n];
    float awv = awb[(h * 16 + s * 4 + p) * N_Q + n];

    float ix = fminf(fmaxf(((bx + ox + 1.f) * fS - 1.f) * 0.5f, 0.f), fS - 1.f);
    float iy = fminf(fmaxf(((by + oy + 1.f) * fS - 1.f) * 0.5f, 0.f), fS - 1.f);
    float iz = fminf(fmaxf(((bz + oz + 1.f) * fS - 1.f) * 0.5f, 0.f), fS - 1.f);

    float x0f = floorf(ix), y0f = floorf(iy), z0f = floorf(iz);
    float fx = ix - x0f, fy = iy - y0f, fz = iz - z0f;
    int x0 = (int)x0f, y0 = (int)y0f, z0 = (int)z0f;
    int x1 = min(x0 + 1, S - 1), y1 = min(y0 + 1, S - 1), z1 = min(z0 + 1, S - 1);

    int r000 = (z0 * S + y0) * S + x0, r001 = (z0 * S + y0) * S + x1;
    int r010 = (z0 * S + y1) * S + x0, r011 = (z0 * S + y1) * S + x1;
    int r100 = (z1 * S + y0) * S + x0, r101 = (z1 * S + y0) * S + x1;
    int r110 = (z1 * S + y1) * S + x0, r111 = (z1 * S + y1) * S + x1;

    float gx1 = fx, gx0 = 1.f - fx;
    float gy1 = fy, gy0 = 1.f - fy;
    float gz1 = fz, gz0 = 1.f - fz;
    float w000 = gz0 * gy0 * gx0 * awv, w001 = gz0 * gy0 * gx1 * awv;
    float w010 = gz0 * gy1 * gx0 * awv, w011 = gz0 * gy1 * gx1 * awv;
    float w100 = gz1 * gy0 * gx0 * awv, w101 = gz1 * gy0 * gx1 * awv;
    float w110 = gz1 * gy1 * gx0 * awv, w111 = gz1 * gy1 * gx1 * awv;

    if (s == 0) {
        const float* Wvh = Wv0 + h * HEAD_DIM * 32;
#pragma unroll
        for (int c8 = 0; c8 < 32; c8 += 8) {
            float u[8] = {0.f, 0.f, 0.f, 0.f, 0.f, 0.f, 0.f, 0.f};
            fma8h(u, w000, srcT + r000 * 32 + c8);
            fma8h(u, w001, srcT + r001 * 32 + c8);
            fma8h(u, w010, srcT + r010 * 32 + c8);
            fma8h(u, w011, srcT + r011 * 32 + c8);
            fma8h(u, w100, srcT + r100 * 32 + c8);
            fma8h(u, w101, srcT + r101 * 32 + c8);
            fma8h(u, w110, srcT + r110 * 32 + c8);
            fma8h(u, w111, srcT + r111 * 32 + c8);
#pragma unroll
            for (int j = 0; j < HEAD_DIM; j++) {
                const float* wp = Wvh + j * 32 + c8;
                float4 wa = ld4(wp), wb = ld4(wp + 4);
                acc[j] = fmaf(wa.x, u[0], fmaf(wa.y, u[1], fmaf(wa.z, u[2], fmaf(wa.w, u[3],
                         fmaf(wb.x, u[4], fmaf(wb.y, u[5], fmaf(wb.z, u[6], fmaf(wb.w, u[7], acc[j]))))))));
            }
        }
    } else {
        const __half* base = srcT + h * HEAD_DIM;
        corner24(acc, w000, base + (size_t)r000 * HIDDEN);
        corner24(acc, w001, base + (size_t)r001 * HIDDEN);
        corner24(acc, w010, base + (size_t)r010 * HIDDEN);
        corner24(acc, w011, base + (size_t)r011 * HIDDEN);
        corner24(acc, w100, base + (size_t)r100 * HIDDEN);
        corner24(acc, w101, base + (size_t)r101 * HIDDEN);
        corner24(acc, w110, base + (size_t)r110 * HIDDEN);
        corner24(acc, w111, base + (size_t)r111 * HIDDEN);
    }

    __half* ab = accb + (size_t)sp * HIDDEN * N_Q;
#pragma unroll
    for (int j = 0; j < HEAD_DIM; j++) ab[(h * HEAD_DIM + j) * N_Q + n] = __float2half(acc[j]);
}

// accsum[i] = sum over the 16 (s,p) fp16 slices
__global__ __launch_bounds__(256)
void accsum_kernel(const __half* __restrict__ accb, float* __restrict__ accsum)
{
    int i = blockIdx.x * 256 + threadIdx.x;
    const int SB8 = HIDDEN * N_Q / 8;
    const uint4* src = (const uint4*)accb;
    float a[8] = {0.f, 0.f, 0.f, 0.f, 0.f, 0.f, 0.f, 0.f};
#pragma unroll
    for (int sp = 0; sp < 16; sp++) {
        uint4 r = src[sp * SB8 + i];
        const __half2* h2 = (const __half2*)&r;
#pragma unroll
        for (int k = 0; k < 4; k++) {
            float2 f = __half22float2(h2[k]);
            a[2 * k] += f.x; a[2 * k + 1] += f.y;
        }
    }
    float4* dst = (float4*)accsum;
    dst[i * 2]     = make_float4(a[0], a[1], a[2], a[3]);
    dst[i * 2 + 1] = make_float4(a[4], a[5], a[6], a[7]);
}

// out[o,n] = sum_c Wout[o,c] * accsum[c,n]
__global__ __launch_bounds__(256)
void outconv_kernel(const float* __restrict__ Wout, const float* __restrict__ accsum,
                    float* __restrict__ out)
{
    __shared__ float xs[HIDDEN * 64];   // 48KB
    __shared__ float Wl[32 * HIDDEN];   // 24KB
    int tid = threadIdx.x;
    int n0 = blockIdx.x * 64;
    int og0 = blockIdx.y * 32;
    for (int k = tid; k < HIDDEN * 64; k += 256) xs[k] = accsum[(size_t)(k >> 6) * N_Q + n0 + (k & 63)];
    for (int k = tid; k < 32 * HIDDEN; k += 256) Wl[k] = Wout[(size_t)og0 * HIDDEN + k];
    __syncthreads();

    int wv = tid >> 6, lane = tid & 63;
    float acc[8];
#pragma unroll
    for (int i = 0; i < 8; i++) acc[i] = 0.f;
    for (int c = 0; c < HIDDEN; c++) {
        float xv = xs[c * 64 + lane];
#pragma unroll
        for (int i = 0; i < 8; i++)
            acc[i] = fmaf(Wl[(wv * 8 + i) * HIDDEN + c], xv, acc[i]);
    }
#pragma unroll
    for (int i = 0; i < 8; i++)
        out[(size_t)(og0 + wv * 8 + i) * N_Q + n0 + lane] = acc[i];
}

// InstanceNorm3d per channel (in-place on d_out)
__global__ __launch_bounds__(256)
void inorm_kernel(float* __restrict__ out, const float* __restrict__ gamma,
                  const float* __restrict__ beta)
{
    int o = blockIdx.x;
    int tid = threadIdx.x;
    float s = 0.f, s2 = 0.f;
    for (int n = tid; n < N_Q; n += 256) {
        float v = out[o * N_Q + n];
        s += v; s2 += v * v;
    }
    __shared__ float rs[256], rs2[256];
    rs[tid] = s; rs2[tid] = s2;
    __syncthreads();
    for (int k = 128; k > 0; k >>= 1) {
        if (tid < k) { rs[tid] += rs[tid + k]; rs2[tid] += rs2[tid + k]; }
        __syncthreads();
    }
    float mu = rs[0] * (1.0f / N_Q);
    float var = rs2[0] * (1.0f / N_Q) - mu * mu;
    float rstd = rsqrtf(var + 1e-5f);
    float g = gamma[o] * rstd;
    float b = beta[o] - mu * g;
    for (int n = tid; n < N_Q; n += 256) {
        out[o * N_Q + n] = fmaf(out[o * N_Q + n], g, b);
    }
}

extern "C" void kernel_launch(void* const* d_in, const int* in_sizes, int n_in,
                              void* d_out, int out_size, void* d_ws, size_t ws_size,
                              hipStream_t stream)
{
    const float* qf    = (const float*)d_in[0];
    const float* v0    = (const float*)d_in[1];
    const float* v1    = (const float*)d_in[2];
    const float* v2    = (const float*)d_in[3];
    const float* v3    = (const float*)d_in[4];
    const float* Wq    = (const float*)d_in[5];
    const float* Wv0   = (const float*)d_in[6];
    const float* Wv1   = (const float*)d_in[7];
    const float* Wv2   = (const float*)d_in[8];
    const float* Wv3   = (const float*)d_in[9];
    const float* Woff  = (const float*)d_in[10];
    const float* boff  = (const float*)d_in[11];
    const float* Wwt   = (const float*)d_in[12];
    const float* bwt   = (const float*)d_in[13];
    const float* Wout  = (const float*)d_in[14];
    const float* gamma = (const float*)d_in[15];
    const float* beta  = (const float*)d_in[16];
    float* out = (float*)d_out;

    float* ws     = (float*)d_ws;
    float*  Wcomb  = ws;                                 // 512*128 = 65536 f
    float*  biasc  = Wcomb  + 65536;                     // 512 f
    float*  offb   = biasc  + 512;                       // 512*4096 = 2097152 f (rows 0..383 off, 384..511 aw)
    float*  awb    = offb   + 384 * 4096;                // alias: rows 384..511
    __half* v0T    = (__half*)(offb + 2097152);          // 262144*32 h (4194304 f)
    __half* val1T  = (__half*)((float*)v0T + 4194304);   // 32768*192 h (3145728 f)
    __half* val2T  = (__half*)((float*)val1T + 3145728); // 4096*192 h (393216 f)
    __half* val3T  = (__half*)((float*)val2T + 393216);  // 512*192 h (49152 f)
    __half* accb   = (__half*)((float*)val3T + 49152);   // 16*192*4096 h (6291456 f)
    float*  accsum = (float*)accb + 6291456;             // 786432 f

    // all independent prep in one launch: v0 transpose + 3 value convs + Wq folding
    prep_kernel<<<6592, 256, 0, stream>>>(v0, v0T, Wv1, v1, val1T, Wv2, v2, val2T,
                                          Wv3, v3, val3T, Woff, Wwt, Wq, boff, bwt,
                                          Wcomb, biasc);
    // offsets (tanh) + attention weights (fused softmax) in one launch
    offaw_kernel<<<dim3(64, 16), 256, 0, stream>>>(Wcomb, biasc, qf, offb);
    // deformable sampling
    sample_kernel<<<2048, 256, 0, stream>>>(offb, awb, v0T, val1T, val2T, val3T, Wv0, accb);
    // reduce the 16 (s,p) fp16 slices
    accsum_kernel<<<384, 256, 0, stream>>>(accb, accsum);
    // final 1x1 conv
    outconv_kernel<<<dim3(64, 4), 256, 0, stream>>>(Wout, accsum, out);
    // instance norm in-place
    inorm_kernel<<<128, 256, 0, stream>>>(out, gamma, beta);
}